// Round 6
// baseline (706.773 us; speedup 1.0000x reference)
//
#include <hip/hip_runtime.h>
#include <cstdint>
#include <cstddef>

#define BN_EPS 1e-5

// ---------------- reductions (fp64 for exact sign decisions) ----------------
// R5: all high-depth fp64 atomics replaced by two-stage partial reductions.
// R2 calibration: same-address fp64 atomicAdd serializes at ~320ns/op; the
// old reduce_cl(a1) was 256-deep per address (~70us hidden), reduce_plane
// 128-deep (~35us). Only reduce_cols2 keeps atomics (depth 8 = ~2.5us).

__global__ void zero_d(double* p, int n) {
  int i = blockIdx.x * blockDim.x + threadIdx.x;
  if (i < n) p[i] = 0.0;
}

// one contiguous HW plane per block: grid (C, N); partial per (c,n), no atomic
__global__ void reduce_plane_p(const float* __restrict__ x, double* __restrict__ pp,
                               int C, int HW) {
  int c = blockIdx.x, n = blockIdx.y;
  const float* p = x + ((long)n * C + c) * HW;
  double s = 0.0, s2 = 0.0;
  for (int i = threadIdx.x; i < HW; i += blockDim.x) {
    double v = (double)p[i];
    s += v; s2 += v * v;
  }
  for (int o = 32; o > 0; o >>= 1) {
    s  += __shfl_down(s, o, 64);
    s2 += __shfl_down(s2, o, 64);
  }
  __shared__ double ls[4], ls2[4];
  int lane = threadIdx.x & 63, w = threadIdx.x >> 6;
  if (lane == 0) { ls[w] = s; ls2[w] = s2; }
  __syncthreads();
  if (threadIdx.x == 0) {
    double a = 0, b = 0;
    for (int i = 0; i < 4; i++) { a += ls[i]; b += ls2[i]; }
    long o = ((long)n * C + c) * 2;
    pp[o] = a; pp[o + 1] = b;
  }
}

__global__ void finalize_plane(const double* __restrict__ pp, double2* __restrict__ st,
                               int C, int N, double cnt) {
  int c = threadIdx.x;
  if (c >= C) return;
  double s = 0.0, s2 = 0.0;
  for (int n = 0; n < N; n++) {
    s  += pp[((long)n * C + c) * 2];
    s2 += pp[((long)n * C + c) * 2 + 1];
  }
  double m = s / cnt;
  double v = s2 / cnt - m * m;
  st[c] = make_double2(m, 1.0 / sqrt(v + BN_EPS));
}

// channel-last reduce stage 1: x [rows][C]; grid (C/64, Y), block 256.
// writes partials part[y][2C], no atomics.
__global__ void reduce_cl_p(const float* __restrict__ x, double* __restrict__ part,
                            int C, long rows) {
  int lane = threadIdx.x & 63, wv = threadIdx.x >> 6;
  int c = blockIdx.x * 64 + lane;
  double s = 0.0, s2 = 0.0;
  for (long r = (long)blockIdx.y * 4 + wv; r < rows; r += (long)gridDim.y * 4) {
    double v = (double)x[r * C + c];
    s += v; s2 += v * v;
  }
  __shared__ double ls[4][64], ls2[4][64];
  ls[wv][lane] = s; ls2[wv][lane] = s2;
  __syncthreads();
  if (threadIdx.x < 64) {
    double a = ls[0][lane] + ls[1][lane] + ls[2][lane] + ls[3][lane];
    double b = ls2[0][lane] + ls2[1][lane] + ls2[2][lane] + ls2[3][lane];
    long o = (long)blockIdx.y * 2 * C + 2 * c;
    part[o] = a; part[o + 1] = b;
  }
}

// stage 2: grid (C/64), block 64; lane c sums Y partials.
__global__ void finalize_parts(const double* __restrict__ part, double2* __restrict__ st,
                               int C, int Y, double cnt) {
  int c = blockIdx.x * 64 + threadIdx.x;
  if (c >= C) return;
  double s = 0.0, s2 = 0.0;
  for (int y = 0; y < Y; y++) {
    s  += part[(long)y * 2 * C + 2 * c];
    s2 += part[(long)y * 2 * C + 2 * c + 1];
  }
  double m = s / cnt;
  double v = s2 / cnt - m * m;
  st[c] = make_double2(m, 1.0 / sqrt(v + BN_EPS));
}

// row-split per-feature reduce of R x F (F % 256 == 0); grid (F/256, RB).
// depth-8 atomics (~2.5us drain) — acceptable.
__global__ void reduce_cols2(const float* __restrict__ x, double* __restrict__ sums,
                             int R, int F, int RS) {
  int f = blockIdx.x * blockDim.x + threadIdx.x;
  int r0 = blockIdx.y * RS, r1 = min(r0 + RS, R);
  double s = 0.0, s2 = 0.0;
  for (int r = r0; r < r1; r++) {
    double v = (double)x[(long)r * F + f];
    s += v; s2 += v * v;
  }
  atomicAdd(&sums[2 * f], s);
  atomicAdd(&sums[2 * f + 1], s2);
}

__global__ void finalize_stats(const double* __restrict__ sums, double2* __restrict__ st,
                               int C, double cnt) {
  int c = blockIdx.x * blockDim.x + threadIdx.x;
  if (c >= C) return;
  double m = sums[2 * c] / cnt;
  double v = sums[2 * c + 1] / cnt - m * m;
  st[c] = make_double2(m, 1.0 / sqrt(v + BN_EPS));
}

// ---------------- ballot-based sign/pack kernels (widened x8/wave) ----------------

__global__ void pack_bits_c1(const float* __restrict__ x, const double2* __restrict__ st,
                             const float* __restrict__ g, const float* __restrict__ b,
                             uint64_t* __restrict__ rows, int nwid) {
  long base = ((long)blockIdx.x * 4 + (threadIdx.x >> 6)) * 8;
  int lane = threadIdx.x & 63;
  for (int j = 0; j < 8; j++) {
    long wid = base + j;
    if (wid >= nwid) return;
    int n = (int)(wid / 192), rem = (int)(wid % 192);
    int ci = rem >> 6, y = rem & 63;
    double2 s = st[ci];
    float xv = x[(((long)n * 3 + ci) * 64 + y) * 64 + lane];
    float xn = (float)(((double)xv - s.x) * s.y) * g[ci] + b[ci];
    uint64_t m = __ballot(xn > 0.f);
    if (lane == 0) rows[wid] = m;
  }
}

__global__ void pack_wc1(const float* __restrict__ w, uint32_t* __restrict__ wm) {
  int co = threadIdx.x;
  uint32_t m = 0;
  for (int j = 0; j < 27; j++) m |= (uint32_t)(w[co * 27 + j] > 0.f) << j;
  wm[co] = m;
}

__global__ void pack_cl(const float* __restrict__ acl, const double2* __restrict__ st,
                        const float* __restrict__ g, const float* __restrict__ b,
                        uint64_t* __restrict__ out, int C, long nwords, int lw) {
  long base = ((long)blockIdx.x * 4 + (threadIdx.x >> 6)) * 8;
  int lane = threadIdx.x & 63;
  for (int j = 0; j < 8; j++) {
    long wid = base + j;
    if (wid >= nwords) return;
    long row = wid >> lw;
    int w = (int)(wid & ((1 << lw) - 1));
    int c = w * 64 + lane;
    double2 s = st[c];
    float xv = acl[row * C + c];
    float xn = (float)(((double)xv - s.x) * s.y) * g[c] + b[c];
    uint64_t m = __ballot(xn > 0.f);
    if (lane == 0) out[wid] = m;
  }
}

__global__ void pack_wconv(const float* __restrict__ w, uint64_t* __restrict__ out,
                           int CO, int CI, int W) {
  int i = blockIdx.x * blockDim.x + threadIdx.x;
  int total = CO * 9 * W;
  if (i >= total) return;
  int wd = i % W;
  int t = i / W;
  int tap = t % 9, co = t / 9;
  uint64_t bits = 0;
  for (int k = 0; k < 64; k++) {
    int ci = wd * 64 + k;
    bits |= (uint64_t)(w[((long)co * CI + ci) * 9 + tap] > 0.f) << k;
  }
  out[i] = bits;
}

// pack sign + nonzero masks; nzc recomputed inline in fc (R2: atomics = 93us).
__global__ void pack_nz(const float* __restrict__ x, const double2* __restrict__ st,
                        const float* __restrict__ g, const float* __restrict__ b,
                        uint64_t* __restrict__ out, int R, int F) {
  int Wf = F >> 6;
  long base = ((long)blockIdx.x * 4 + (threadIdx.x >> 6)) * 8;
  int lane = threadIdx.x & 63;
  for (int j = 0; j < 8; j++) {
    long wid = base + j;
    if (wid >= (long)R * Wf) return;
    long r = wid / Wf;
    int w = (int)(wid % Wf);
    int f = w * 64 + lane;
    double2 s = st[f];
    double d = (double)x[r * F + f] - s.x;  // exact for lattice values
    float xn = (float)(d * s.y) * g[f] + b[f];
    uint64_t sm = __ballot(xn > 0.f);
    uint64_t nm = __ballot(d != 0.0);
    if (lane == 0) { out[2 * wid] = sm; out[2 * wid + 1] = nm; }
  }
}

// transposed weight pack: out [wd][O] so fc weight loads are lane-coalesced
__global__ void pack_wfc2_t(const float* __restrict__ w, uint64_t* __restrict__ out,
                            int O, int F) {
  int Wf = F >> 6;
  long base = ((long)blockIdx.x * 4 + (threadIdx.x >> 6)) * 8;
  int lane = threadIdx.x & 63;
  for (int j = 0; j < 8; j++) {
    long wid = base + j;
    if (wid >= (long)O * Wf) return;
    long o = wid / Wf;
    int wd = (int)(wid % Wf);
    uint64_t m = __ballot(w[o * F + wd * 64 + lane] > 0.f);
    if (lane == 0) out[(long)wd * O + o] = m;
  }
}

// ---------------- fused conv + maxpool + prelu ----------------

// conv1 via 27-bit xnor-popcount; out channel-last [n][961][128]
__global__ __launch_bounds__(256) void conv1_pool3(const uint64_t* __restrict__ rows,
                                                   const uint32_t* __restrict__ wm,
                                                   const float* __restrict__ cp,
                                                   float* __restrict__ out) {
  __shared__ uint64_t rL[192];
  __shared__ uint32_t wL[128];
  __shared__ uint32_t mL[61 * 4];
  int n = blockIdx.y, chunk = blockIdx.x, t = threadIdx.x;
  if (t < 192) rL[t] = rows[n * 192 + t];
  if (t < 128) wL[t] = wm[t];
  __syncthreads();
  if (t < 244) {
    int pl = t >> 2, quad = t & 3;
    int pos = chunk * 61 + pl;
    if (pos < 961) {
      int py = pos / 31, px = pos - py * 31;
      int cy = 2 * py + (quad >> 1), cx = 2 * px + (quad & 1);
      uint32_t m = 0;
#pragma unroll
      for (int ci = 0; ci < 3; ci++)
#pragma unroll
        for (int ky = 0; ky < 3; ky++)
          m |= (uint32_t)((rL[ci * 64 + cy + ky] >> cx) & 7) << (ci * 9 + ky * 3);
      mL[pl * 4 + quad] = m;
    }
  }
  __syncthreads();
  int co = t & 127, slot = t >> 7;
  float alpha = cp[0];
  uint32_t w = wL[co];
  for (int i = slot; i < 61; i += 2) {
    int pos = chunk * 61 + i;
    if (pos >= 961) break;
    int p0 = __popc(mL[4 * i] ^ w);
    int p1 = __popc(mL[4 * i + 1] ^ w);
    int p2 = __popc(mL[4 * i + 2] ^ w);
    int p3 = __popc(mL[4 * i + 3] ^ w);
    int dot = 27 - 2 * min(min(p0, p1), min(p2, p3));
    float f = (float)dot;
    out[((long)n * 961 + pos) * 128 + co] = dot >= 0 ? f : alpha * f;
  }
}

// conv2 = R3's convp_carry, reverted VERBATIM (round algebra: it ran at
// ~15-25us; R4's half-wave shfl redesign regressed to 81us). Full 64-co
// wave, 2-column register carry, small static-indexed arrays stay in
// registers under waves_per_eu(3,4) (cap 128 >= ~112 live).
template <int W, int IH, int PH, int CHUNK, bool CL>
__global__ __attribute__((amdgpu_flat_work_group_size(256, 256),
                          amdgpu_waves_per_eu(3, 4)))
void convp_carry(const uint64_t* __restrict__ in, const uint64_t* __restrict__ wt,
                 const float* __restrict__ cp, float* __restrict__ out, int CO) {
  __shared__ uint64_t sIn[10 * IH * W];
  int n = blockIdx.y;
  int cg = blockIdx.x / CHUNK, chunk = blockIdx.x % CHUNK;
  int t = threadIdx.x, lane = t & 63, slot = t >> 6;
  int r0 = chunk * 8;
  int nr = min(10, IH - r0);
  const uint64_t* src = in + ((long)n * IH + r0) * (IH * W);
  for (int i = t; i < nr * IH * W; i += 256) sIn[i] = src[i];
  int co = cg * 64 + lane;
  uint64_t wr[9 * W];
  const uint64_t* wg = wt + (long)co * (9 * W);
#pragma unroll
  for (int i = 0; i < 9 * W; i++) wr[i] = wg[i];
  __syncthreads();
  int py = chunk * 4 + slot;
  if (py >= PH) return;
  float alpha = cp[0];
  const int K = 9 * 64 * W;
  const uint64_t* base = &sIn[(2 * slot) * (IH * W)];  // local row = 2*slot+cy
  uint64_t c[4][2 * W];
#pragma unroll
  for (int cy = 0; cy < 4; cy++) {
    const uint64_t* p = &base[(cy * IH) * W];
#pragma unroll
    for (int j = 0; j < 2 * W; j++) c[cy][j] = p[j];
  }
#pragma unroll
  for (int px = 0; px < PH; px++) {
    int a00 = 0, a01 = 0, a10 = 0, a11 = 0;
#pragma unroll
    for (int cy = 0; cy < 4; cy++) {
      uint64_t f[2 * W];
      const uint64_t* fp = &base[(cy * IH + 2 * px + 2) * W];
#pragma unroll
      for (int j = 0; j < 2 * W; j++) f[j] = fp[j];
#pragma unroll
      for (int col = 0; col < 4; col++) {
#pragma unroll
        for (int wd = 0; wd < W; wd++) {
          uint64_t v = (col < 2) ? c[cy][col * W + wd] : f[(col - 2) * W + wd];
#pragma unroll
          for (int dy = 0; dy < 2; dy++) {
            int ky = cy - dy;
            if (ky < 0 || ky > 2) continue;  // compile-time folded
#pragma unroll
            for (int dx = 0; dx < 2; dx++) {
              int kx = col - dx;
              if (kx < 0 || kx > 2) continue;  // compile-time folded
              int p = __popcll(v ^ wr[(ky * 3 + kx) * W + wd]);
              if (dy == 0) { if (dx == 0) a00 += p; else a01 += p; }
              else         { if (dx == 0) a10 += p; else a11 += p; }
            }
          }
        }
      }
#pragma unroll
      for (int j = 0; j < 2 * W; j++) c[cy][j] = f[j];
    }
    int dot = K - 2 * min(min(a00, a01), min(a10, a11));
    float f = (float)dot;
    long idx = CL ? (((long)n * PH * PH + py * PH + px) * CO + co)
                  : (((long)n * CO + co) * PH * PH + (py * PH + px));
    out[idx] = dot >= 0 ? f : alpha * f;
  }
}

// conv3 = R4's convs3 (kept): half-wave split, NAMED scalar weights only,
// no scratch (R4: FETCH 2.5MB). W=4 arrays cannot stay in registers (R3:
// 682MB scratch traffic), so the half-wave form is the right one here.
#define TAP2(acc, P, wa, wb) acc += __popcll((P).x ^ (wa)) + __popcll((P).y ^ (wb));
#define ROWT(aL, aR, pA, pB, pC, pD, WX, WY, WZ)                \
  TAP2(aL, pA, WX.x, WX.y) TAP2(aL, pB, WY.x, WY.y)             \
  TAP2(aL, pC, WZ.x, WZ.y)                                      \
  TAP2(aR, pB, WX.x, WX.y) TAP2(aR, pC, WY.x, WY.y)             \
  TAP2(aR, pD, WZ.x, WZ.y)

__global__ __attribute__((amdgpu_flat_work_group_size(256, 256),
                          amdgpu_waves_per_eu(4, 6)))
void convs3(const uint64_t* __restrict__ in, const uint64_t* __restrict__ wt,
            const float* __restrict__ cp, float* __restrict__ out) {
  __shared__ uint64_t sIn[14 * 14 * 4];
  int n = blockIdx.y, cg = blockIdx.x;
  int t = threadIdx.x, lane = t & 63, slot = t >> 6;
  const uint64_t* src = in + (long)n * 784;
  for (int i = t; i < 784; i += 256) sIn[i] = src[i];
  int h = lane >> 5;
  int co = cg * 32 + (lane & 31);
  const uint64_t* wg = wt + co * 36 + 2 * h;
  ulonglong2 W0 = *(const ulonglong2*)(wg + 0);
  ulonglong2 W1 = *(const ulonglong2*)(wg + 4);
  ulonglong2 W2 = *(const ulonglong2*)(wg + 8);
  ulonglong2 W3 = *(const ulonglong2*)(wg + 12);
  ulonglong2 W4 = *(const ulonglong2*)(wg + 16);
  ulonglong2 W5 = *(const ulonglong2*)(wg + 20);
  ulonglong2 W6 = *(const ulonglong2*)(wg + 24);
  ulonglong2 W7 = *(const ulonglong2*)(wg + 28);
  ulonglong2 W8 = *(const ulonglong2*)(wg + 32);
  __syncthreads();
  float alpha = cp[0];
  float* outb = out + ((long)n * 512 + co) * 36;
#pragma unroll
  for (int k = 0; k < 9; k++) {
    int pos = slot + 4 * k;  // 0..35
    int py = pos / 6, px = pos - py * 6;
    const uint64_t* q = sIn + ((2 * py) * 14 + 2 * px) * 4 + 2 * h;
    int a00 = 0, a01 = 0, a10 = 0, a11 = 0;
    {
      ulonglong2 p0 = *(const ulonglong2*)(q + 0);
      ulonglong2 p1 = *(const ulonglong2*)(q + 4);
      ulonglong2 p2 = *(const ulonglong2*)(q + 8);
      ulonglong2 p3 = *(const ulonglong2*)(q + 12);
      ROWT(a00, a01, p0, p1, p2, p3, W0, W1, W2)
    }
    {
      const uint64_t* q1 = q + 56;
      ulonglong2 p0 = *(const ulonglong2*)(q1 + 0);
      ulonglong2 p1 = *(const ulonglong2*)(q1 + 4);
      ulonglong2 p2 = *(const ulonglong2*)(q1 + 8);
      ulonglong2 p3 = *(const ulonglong2*)(q1 + 12);
      ROWT(a00, a01, p0, p1, p2, p3, W3, W4, W5)
      ROWT(a10, a11, p0, p1, p2, p3, W0, W1, W2)
    }
    {
      const uint64_t* q2 = q + 112;
      ulonglong2 p0 = *(const ulonglong2*)(q2 + 0);
      ulonglong2 p1 = *(const ulonglong2*)(q2 + 4);
      ulonglong2 p2 = *(const ulonglong2*)(q2 + 8);
      ulonglong2 p3 = *(const ulonglong2*)(q2 + 12);
      ROWT(a00, a01, p0, p1, p2, p3, W6, W7, W8)
      ROWT(a10, a11, p0, p1, p2, p3, W3, W4, W5)
    }
    {
      const uint64_t* q3 = q + 168;
      ulonglong2 p0 = *(const ulonglong2*)(q3 + 0);
      ulonglong2 p1 = *(const ulonglong2*)(q3 + 4);
      ulonglong2 p2 = *(const ulonglong2*)(q3 + 8);
      ulonglong2 p3 = *(const ulonglong2*)(q3 + 12);
      ROWT(a10, a11, p0, p1, p2, p3, W6, W7, W8)
    }
    int t00 = a00 + __shfl_xor(a00, 32);
    int t01 = a01 + __shfl_xor(a01, 32);
    int t10 = a10 + __shfl_xor(a10, 32);
    int t11 = a11 + __shfl_xor(a11, 32);
    if (h == 0) {
      int dot = 2304 - 2 * min(min(t00, t01), min(t10, t11));
      float ff = (float)dot;
      outb[pos] = dot >= 0 ? ff : alpha * ff;
    }
  }
}

// ---------------- binary fc (with nonzero mask on activations) ----------------

__global__ void fc_bin2(const uint64_t* __restrict__ xp, const uint64_t* __restrict__ wp_t,
                        const float* __restrict__ cp, float* __restrict__ out,
                        int O, int Wf) {
  __shared__ uint64_t xs[2][288], xz[2][288];
  int r0 = blockIdx.y * 2;
  for (int i = threadIdx.x; i < 2 * Wf; i += blockDim.x) {
    int rr = i / Wf, wd = i - rr * Wf;
    xs[rr][wd] = xp[(((long)(r0 + rr)) * Wf + wd) * 2];
    xz[rr][wd] = xp[(((long)(r0 + rr)) * Wf + wd) * 2 + 1];
  }
  __syncthreads();
  int o = blockIdx.x * blockDim.x + threadIdx.x;
  if (o >= O) return;
  int pc0 = 0, pc1 = 0, nz0 = 0, nz1 = 0;
  for (int wd = 0; wd < Wf; wd++) {
    uint64_t w = wp_t[(long)wd * O + o];
    uint64_t z0 = xz[0][wd], z1 = xz[1][wd];
    pc0 += __popcll((xs[0][wd] ^ w) & z0);
    pc1 += __popcll((xs[1][wd] ^ w) & z1);
    nz0 += __popcll(z0);
    nz1 += __popcll(z1);
  }
  float alpha = cp[0];
  int d0 = nz0 - 2 * pc0, d1 = nz1 - 2 * pc1;
  float f0 = (float)d0, f1 = (float)d1;
  out[(long)r0 * O + o] = d0 >= 0 ? f0 : alpha * f0;
  out[(long)(r0 + 1) * O + o] = d1 >= 0 ? f1 : alpha * f1;
}

__global__ void fc_bin_scale(const uint64_t* __restrict__ xp, const uint64_t* __restrict__ wp_t,
                             const float* __restrict__ cp, const float* __restrict__ scale,
                             float* __restrict__ out, int R, int O, int Wf) {
  int i = blockIdx.x * blockDim.x + threadIdx.x;
  if (i >= R * O) return;
  int o = i % O, r = i / O;
  int pc = 0, nzc = 0;
  for (int wd = 0; wd < Wf; wd++) {
    uint64_t nz = xp[((long)r * Wf + wd) * 2 + 1];
    pc += __popcll((xp[((long)r * Wf + wd) * 2] ^ wp_t[(long)wd * O + o]) & nz);
    nzc += __popcll(nz);
  }
  int dot = nzc - 2 * pc;
  float f = (float)dot;
  float alpha = cp[0];
  f = dot >= 0 ? f : alpha * f;
  out[i] = f * scale[0];
}

// ---------------- launch ----------------

extern "C" void kernel_launch(void* const* d_in, const int* in_sizes, int n_in,
                              void* d_out, int out_size, void* d_ws, size_t ws_size,
                              hipStream_t stream) {
  const float* x   = (const float*)d_in[0];
  const float* cg0 = (const float*)d_in[1];
  const float* cb0 = (const float*)d_in[2];
  const float* cw0 = (const float*)d_in[3];
  const float* cp0 = (const float*)d_in[4];
  const float* cg1 = (const float*)d_in[5];
  const float* cb1 = (const float*)d_in[6];
  const float* cw1 = (const float*)d_in[7];
  const float* cp1 = (const float*)d_in[8];
  const float* cg2 = (const float*)d_in[9];
  const float* cb2 = (const float*)d_in[10];
  const float* cw2 = (const float*)d_in[11];
  const float* cp2 = (const float*)d_in[12];
  const float* fg0 = (const float*)d_in[13];
  const float* fb0 = (const float*)d_in[14];
  const float* fw0 = (const float*)d_in[15];
  const float* fp0 = (const float*)d_in[16];
  const float* fg1 = (const float*)d_in[17];
  const float* fb1 = (const float*)d_in[18];
  const float* fw1 = (const float*)d_in[19];
  const float* fp1 = (const float*)d_in[20];
  const float* scl = (const float*)d_in[21];

  char* ws = (char*)d_ws;
  size_t off = 0;
  auto alloc = [&](size_t bytes) {
    size_t r = off;
    off += (bytes + 255) & ~(size_t)255;
    return r;
  };
  const int C0_OFF = 0, C1_OFF = 16, C2_OFF = 160, C3_OFF = 448, C4_OFF = 18944;
  const int NCH = 19968;

  double*   sums  = (double*)(ws + alloc((size_t)NCH * 2 * sizeof(double)));
  double2*  stats = (double2*)(ws + alloc((size_t)NCH * sizeof(double2)));
  double*   parts = (double*)(ws + alloc(512L * 512 * sizeof(double)));  // 2-stage partials
  double*   pplane= (double*)(ws + alloc(128L * 3 * 2 * sizeof(double)));
  uint64_t* rows0 = (uint64_t*)(ws + alloc(128L * 3 * 64 * 8));
  uint32_t* wm1   = (uint32_t*)(ws + alloc(128L * 4));
  float*    a1    = (float*)(ws + alloc(128L * 961 * 128 * 4));   // channel-last
  uint64_t* s1p   = (uint64_t*)(ws + alloc(128L * 961 * 2 * 8));
  uint64_t* w1p   = (uint64_t*)(ws + alloc(256L * 9 * 2 * 8));
  float*    a2    = (float*)(ws + alloc(128L * 196 * 256 * 4));   // channel-last
  uint64_t* s2p   = (uint64_t*)(ws + alloc(128L * 196 * 4 * 8));
  uint64_t* w2p   = (uint64_t*)(ws + alloc(512L * 9 * 4 * 8));
  float*    a3    = (float*)(ws + alloc(128L * 512 * 36 * 4));    // channel-major (reshape order)
  uint64_t* s3p   = (uint64_t*)(ws + alloc(128L * 288 * 2 * 8));
  uint64_t* w3p   = (uint64_t*)(ws + alloc(1024L * 288 * 8));     // transposed [288][1024]
  float*    f1    = (float*)(ws + alloc(128L * 1024 * 4));
  uint64_t* s4p   = (uint64_t*)(ws + alloc(128L * 16 * 2 * 8));
  uint64_t* w4p   = (uint64_t*)(ws + alloc(10L * 16 * 8));        // transposed [16][10]

  const int B = 256;

  // only the fc-stat atomic regions (C3,C4) need zeroing now
  zero_d<<<dim3(153), B, 0, stream>>>(sums + 2 * C3_OFF, (NCH - C3_OFF) * 2);

  // ---- block 0: BN(x) -> sign-bits -> conv1(popcount) -> pool -> prelu ----
  reduce_plane_p<<<dim3(3, 128), B, 0, stream>>>(x, pplane, 3, 4096);
  finalize_plane<<<1, 64, 0, stream>>>(pplane, stats + C0_OFF, 3, 128, 524288.0);
  pack_bits_c1<<<dim3(768), B, 0, stream>>>(x, stats + C0_OFF, cg0, cb0, rows0, 24576);
  pack_wc1<<<1, 128, 0, stream>>>(cw0, wm1);
  conv1_pool3<<<dim3(16, 128), B, 0, stream>>>(rows0, wm1, cp0, a1);

  // ---- block 1: BN(a1) -> pack -> conv2 -> pool -> prelu ----
  reduce_cl_p<<<dim3(2, 512), B, 0, stream>>>(a1, parts, 128, 123008L);
  finalize_parts<<<2, 64, 0, stream>>>(parts, stats + C1_OFF, 128, 512, 123008.0);
  pack_cl<<<dim3(7688), B, 0, stream>>>(a1, stats + C1_OFF, cg1, cb1, s1p, 128, 246016L, 1);
  pack_wconv<<<dim3(18), B, 0, stream>>>(cw1, w1p, 256, 128, 2);
  // 4 co-groups x 4 py-chunks
  convp_carry<2, 31, 14, 4, true><<<dim3(16, 128), B, 0, stream>>>(s1p, w1p, cp1, a2, 256);

  // ---- block 2: BN(a2) -> pack -> conv3 -> pool -> prelu ----
  reduce_cl_p<<<dim3(4, 256), B, 0, stream>>>(a2, parts, 256, 25088L);
  finalize_parts<<<4, 64, 0, stream>>>(parts, stats + C2_OFF, 256, 256, 25088.0);
  pack_cl<<<dim3(3136), B, 0, stream>>>(a2, stats + C2_OFF, cg2, cb2, s2p, 256, 100352L, 2);
  pack_wconv<<<dim3(72), B, 0, stream>>>(cw2, w2p, 512, 256, 4);
  // 16 co-groups (32 co each)
  convs3<<<dim3(16, 128), B, 0, stream>>>(s2p, w2p, cp2, a3);

  // ---- fc 0: BN1d -> sign @ sign(W).T -> prelu ----
  reduce_cols2<<<dim3(72, 8), B, 0, stream>>>(a3, sums + 2 * C3_OFF, 128, 18432, 16);
  finalize_stats<<<dim3(72), B, 0, stream>>>(sums + 2 * C3_OFF, stats + C3_OFF, 18432, 128.0);
  pack_nz<<<dim3(1152), B, 0, stream>>>(a3, stats + C3_OFF, fg0, fb0, s3p, 128, 18432);
  pack_wfc2_t<<<dim3(9216), B, 0, stream>>>(fw0, w3p, 1024, 18432);
  fc_bin2<<<dim3(4, 64), B, 0, stream>>>(s3p, w3p, fp0, f1, 1024, 288);

  // ---- fc 1: BN1d -> sign @ sign(W).T -> prelu -> scale ----
  reduce_cols2<<<dim3(4, 8), B, 0, stream>>>(f1, sums + 2 * C4_OFF, 128, 1024, 16);
  finalize_stats<<<dim3(4), B, 0, stream>>>(sums + 2 * C4_OFF, stats + C4_OFF, 1024, 128.0);
  pack_nz<<<dim3(64), B, 0, stream>>>(f1, stats + C4_OFF, fg1, fb1, s4p, 128, 1024);
  pack_wfc2_t<<<dim3(5), B, 0, stream>>>(fw1, w4p, 10, 1024);
  fc_bin_scale<<<dim3(5), B, 0, stream>>>(s4p, w4p, fp1, scl, (float*)d_out, 128, 10, 16);
}

// Round 7
// 511.852 us; speedup vs baseline: 1.3808x; 1.3808x over previous
//
#include <hip/hip_runtime.h>
#include <cstdint>
#include <cstddef>

#define BN_EPS 1e-5

// ---------------- reductions (fp64 for exact sign decisions) ----------------
// R5/R7: no deep same-address atomics (R2: ~320ns per serialized fp64 RMW)
// AND no serial single-wave finalize loops (R6: finalize_parts with 128
// threads total = 126us latency-bound tail). Stage 1 writes partials in
// parallel; stage 2 is one BLOCK per channel, 256 threads striding Y.

__global__ void zero_d(double* p, int n) {
  int i = blockIdx.x * blockDim.x + threadIdx.x;
  if (i < n) p[i] = 0.0;
}

// one contiguous HW plane per block: grid (C, N); partial per (c,n), no atomic
__global__ void reduce_plane_p(const float* __restrict__ x, double* __restrict__ pp,
                               int C, int HW) {
  int c = blockIdx.x, n = blockIdx.y;
  const float* p = x + ((long)n * C + c) * HW;
  double s = 0.0, s2 = 0.0;
  for (int i = threadIdx.x; i < HW; i += blockDim.x) {
    double v = (double)p[i];
    s += v; s2 += v * v;
  }
  for (int o = 32; o > 0; o >>= 1) {
    s  += __shfl_down(s, o, 64);
    s2 += __shfl_down(s2, o, 64);
  }
  __shared__ double ls[4], ls2[4];
  int lane = threadIdx.x & 63, w = threadIdx.x >> 6;
  if (lane == 0) { ls[w] = s; ls2[w] = s2; }
  __syncthreads();
  if (threadIdx.x == 0) {
    double a = 0, b = 0;
    for (int i = 0; i < 4; i++) { a += ls[i]; b += ls2[i]; }
    long o = ((long)n * C + c) * 2;
    pp[o] = a; pp[o + 1] = b;
  }
}

// parallel plane finalize: grid (C), block 128; thread n handles partial n.
__global__ void finalize_plane_par(const double* __restrict__ pp, double2* __restrict__ st,
                                   int C, int N, double cnt) {
  int c = blockIdx.x;
  double s = 0.0, s2 = 0.0;
  for (int n = threadIdx.x; n < N; n += blockDim.x) {
    long o = ((long)n * C + c) * 2;
    s  += pp[o];
    s2 += pp[o + 1];
  }
  for (int o = 32; o > 0; o >>= 1) {
    s  += __shfl_down(s, o, 64);
    s2 += __shfl_down(s2, o, 64);
  }
  __shared__ double ls[2], ls2[2];
  int lane = threadIdx.x & 63, w = threadIdx.x >> 6;
  if (lane == 0) { ls[w] = s; ls2[w] = s2; }
  __syncthreads();
  if (threadIdx.x == 0) {
    double a = ls[0] + ls[1], b = ls2[0] + ls2[1];
    double m = a / cnt;
    double v = b / cnt - m * m;
    st[c] = make_double2(m, 1.0 / sqrt(v + BN_EPS));
  }
}

// channel-last reduce stage 1: x [rows][C]; grid (C/64, Y), block 256.
// writes partials part[y][2C], no atomics.
__global__ void reduce_cl_p(const float* __restrict__ x, double* __restrict__ part,
                            int C, long rows) {
  int lane = threadIdx.x & 63, wv = threadIdx.x >> 6;
  int c = blockIdx.x * 64 + lane;
  double s = 0.0, s2 = 0.0;
  for (long r = (long)blockIdx.y * 4 + wv; r < rows; r += (long)gridDim.y * 4) {
    double v = (double)x[r * C + c];
    s += v; s2 += v * v;
  }
  __shared__ double ls[4][64], ls2[4][64];
  ls[wv][lane] = s; ls2[wv][lane] = s2;
  __syncthreads();
  if (threadIdx.x < 64) {
    double a = ls[0][lane] + ls[1][lane] + ls[2][lane] + ls[3][lane];
    double b = ls2[0][lane] + ls2[1][lane] + ls2[2][lane] + ls2[3][lane];
    long o = (long)blockIdx.y * 2 * C + 2 * c;
    part[o] = a; part[o + 1] = b;
  }
}

// parallel stage 2: one block per channel, 256 threads stride Y (R6 fix:
// the 64-thread serial version was 126us latency-bound; this is ~3us).
__global__ void finalize_parts_par(const double* __restrict__ part, double2* __restrict__ st,
                                   int C, int Y, double cnt) {
  int c = blockIdx.x;
  double s = 0.0, s2 = 0.0;
  for (int y = threadIdx.x; y < Y; y += blockDim.x) {
    long o = (long)y * 2 * C + 2 * c;
    s  += part[o];
    s2 += part[o + 1];
  }
  for (int o = 32; o > 0; o >>= 1) {
    s  += __shfl_down(s, o, 64);
    s2 += __shfl_down(s2, o, 64);
  }
  __shared__ double ls[4], ls2[4];
  int lane = threadIdx.x & 63, w = threadIdx.x >> 6;
  if (lane == 0) { ls[w] = s; ls2[w] = s2; }
  __syncthreads();
  if (threadIdx.x == 0) {
    double a = ls[0] + ls[1] + ls[2] + ls[3];
    double b = ls2[0] + ls2[1] + ls2[2] + ls2[3];
    double m = a / cnt;
    double v = b / cnt - m * m;
    st[c] = make_double2(m, 1.0 / sqrt(v + BN_EPS));
  }
}

// row-split per-feature reduce of R x F (F % 256 == 0); grid (F/256, RB).
// depth-8 atomics (~2.5us drain) — acceptable.
__global__ void reduce_cols2(const float* __restrict__ x, double* __restrict__ sums,
                             int R, int F, int RS) {
  int f = blockIdx.x * blockDim.x + threadIdx.x;
  int r0 = blockIdx.y * RS, r1 = min(r0 + RS, R);
  double s = 0.0, s2 = 0.0;
  for (int r = r0; r < r1; r++) {
    double v = (double)x[(long)r * F + f];
    s += v; s2 += v * v;
  }
  atomicAdd(&sums[2 * f], s);
  atomicAdd(&sums[2 * f + 1], s2);
}

__global__ void finalize_stats(const double* __restrict__ sums, double2* __restrict__ st,
                               int C, double cnt) {
  int c = blockIdx.x * blockDim.x + threadIdx.x;
  if (c >= C) return;
  double m = sums[2 * c] / cnt;
  double v = sums[2 * c + 1] / cnt - m * m;
  st[c] = make_double2(m, 1.0 / sqrt(v + BN_EPS));
}

// ---------------- ballot-based sign/pack kernels (widened x8/wave) ----------------

__global__ void pack_bits_c1(const float* __restrict__ x, const double2* __restrict__ st,
                             const float* __restrict__ g, const float* __restrict__ b,
                             uint64_t* __restrict__ rows, int nwid) {
  long base = ((long)blockIdx.x * 4 + (threadIdx.x >> 6)) * 8;
  int lane = threadIdx.x & 63;
  for (int j = 0; j < 8; j++) {
    long wid = base + j;
    if (wid >= nwid) return;
    int n = (int)(wid / 192), rem = (int)(wid % 192);
    int ci = rem >> 6, y = rem & 63;
    double2 s = st[ci];
    float xv = x[(((long)n * 3 + ci) * 64 + y) * 64 + lane];
    float xn = (float)(((double)xv - s.x) * s.y) * g[ci] + b[ci];
    uint64_t m = __ballot(xn > 0.f);
    if (lane == 0) rows[wid] = m;
  }
}

__global__ void pack_wc1(const float* __restrict__ w, uint32_t* __restrict__ wm) {
  int co = threadIdx.x;
  uint32_t m = 0;
  for (int j = 0; j < 27; j++) m |= (uint32_t)(w[co * 27 + j] > 0.f) << j;
  wm[co] = m;
}

__global__ void pack_cl(const float* __restrict__ acl, const double2* __restrict__ st,
                        const float* __restrict__ g, const float* __restrict__ b,
                        uint64_t* __restrict__ out, int C, long nwords, int lw) {
  long base = ((long)blockIdx.x * 4 + (threadIdx.x >> 6)) * 8;
  int lane = threadIdx.x & 63;
  for (int j = 0; j < 8; j++) {
    long wid = base + j;
    if (wid >= nwords) return;
    long row = wid >> lw;
    int w = (int)(wid & ((1 << lw) - 1));
    int c = w * 64 + lane;
    double2 s = st[c];
    float xv = acl[row * C + c];
    float xn = (float)(((double)xv - s.x) * s.y) * g[c] + b[c];
    uint64_t m = __ballot(xn > 0.f);
    if (lane == 0) out[wid] = m;
  }
}

__global__ void pack_wconv(const float* __restrict__ w, uint64_t* __restrict__ out,
                           int CO, int CI, int W) {
  int i = blockIdx.x * blockDim.x + threadIdx.x;
  int total = CO * 9 * W;
  if (i >= total) return;
  int wd = i % W;
  int t = i / W;
  int tap = t % 9, co = t / 9;
  uint64_t bits = 0;
  for (int k = 0; k < 64; k++) {
    int ci = wd * 64 + k;
    bits |= (uint64_t)(w[((long)co * CI + ci) * 9 + tap] > 0.f) << k;
  }
  out[i] = bits;
}

// pack sign + nonzero masks; nzc recomputed inline in fc (R2: atomics = 93us).
__global__ void pack_nz(const float* __restrict__ x, const double2* __restrict__ st,
                        const float* __restrict__ g, const float* __restrict__ b,
                        uint64_t* __restrict__ out, int R, int F) {
  int Wf = F >> 6;
  long base = ((long)blockIdx.x * 4 + (threadIdx.x >> 6)) * 8;
  int lane = threadIdx.x & 63;
  for (int j = 0; j < 8; j++) {
    long wid = base + j;
    if (wid >= (long)R * Wf) return;
    long r = wid / Wf;
    int w = (int)(wid % Wf);
    int f = w * 64 + lane;
    double2 s = st[f];
    double d = (double)x[r * F + f] - s.x;  // exact for lattice values
    float xn = (float)(d * s.y) * g[f] + b[f];
    uint64_t sm = __ballot(xn > 0.f);
    uint64_t nm = __ballot(d != 0.0);
    if (lane == 0) { out[2 * wid] = sm; out[2 * wid + 1] = nm; }
  }
}

// transposed weight pack: out [wd][O] so fc weight loads are lane-coalesced
__global__ void pack_wfc2_t(const float* __restrict__ w, uint64_t* __restrict__ out,
                            int O, int F) {
  int Wf = F >> 6;
  long base = ((long)blockIdx.x * 4 + (threadIdx.x >> 6)) * 8;
  int lane = threadIdx.x & 63;
  for (int j = 0; j < 8; j++) {
    long wid = base + j;
    if (wid >= (long)O * Wf) return;
    long o = wid / Wf;
    int wd = (int)(wid % Wf);
    uint64_t m = __ballot(w[o * F + wd * 64 + lane] > 0.f);
    if (lane == 0) out[(long)wd * O + o] = m;
  }
}

// ---------------- fused conv + maxpool + prelu ----------------

// conv1 via 27-bit xnor-popcount; out channel-last [n][961][128]
__global__ __launch_bounds__(256) void conv1_pool3(const uint64_t* __restrict__ rows,
                                                   const uint32_t* __restrict__ wm,
                                                   const float* __restrict__ cp,
                                                   float* __restrict__ out) {
  __shared__ uint64_t rL[192];
  __shared__ uint32_t wL[128];
  __shared__ uint32_t mL[61 * 4];
  int n = blockIdx.y, chunk = blockIdx.x, t = threadIdx.x;
  if (t < 192) rL[t] = rows[n * 192 + t];
  if (t < 128) wL[t] = wm[t];
  __syncthreads();
  if (t < 244) {
    int pl = t >> 2, quad = t & 3;
    int pos = chunk * 61 + pl;
    if (pos < 961) {
      int py = pos / 31, px = pos - py * 31;
      int cy = 2 * py + (quad >> 1), cx = 2 * px + (quad & 1);
      uint32_t m = 0;
#pragma unroll
      for (int ci = 0; ci < 3; ci++)
#pragma unroll
        for (int ky = 0; ky < 3; ky++)
          m |= (uint32_t)((rL[ci * 64 + cy + ky] >> cx) & 7) << (ci * 9 + ky * 3);
      mL[pl * 4 + quad] = m;
    }
  }
  __syncthreads();
  int co = t & 127, slot = t >> 7;
  float alpha = cp[0];
  uint32_t w = wL[co];
  for (int i = slot; i < 61; i += 2) {
    int pos = chunk * 61 + i;
    if (pos >= 961) break;
    int p0 = __popc(mL[4 * i] ^ w);
    int p1 = __popc(mL[4 * i + 1] ^ w);
    int p2 = __popc(mL[4 * i + 2] ^ w);
    int p3 = __popc(mL[4 * i + 3] ^ w);
    int dot = 27 - 2 * min(min(p0, p1), min(p2, p3));
    float f = (float)dot;
    out[((long)n * 961 + pos) * 128 + co] = dot >= 0 ? f : alpha * f;
  }
}

// conv2 = R3's convp_carry (round algebra: ~15-25us; R4's half-wave shfl
// redesign regressed to 81us). Full 64-co wave, 2-column register carry,
// small static-indexed arrays stay in registers under waves_per_eu(3,4).
template <int W, int IH, int PH, int CHUNK, bool CL>
__global__ __attribute__((amdgpu_flat_work_group_size(256, 256),
                          amdgpu_waves_per_eu(3, 4)))
void convp_carry(const uint64_t* __restrict__ in, const uint64_t* __restrict__ wt,
                 const float* __restrict__ cp, float* __restrict__ out, int CO) {
  __shared__ uint64_t sIn[10 * IH * W];
  int n = blockIdx.y;
  int cg = blockIdx.x / CHUNK, chunk = blockIdx.x % CHUNK;
  int t = threadIdx.x, lane = t & 63, slot = t >> 6;
  int r0 = chunk * 8;
  int nr = min(10, IH - r0);
  const uint64_t* src = in + ((long)n * IH + r0) * (IH * W);
  for (int i = t; i < nr * IH * W; i += 256) sIn[i] = src[i];
  int co = cg * 64 + lane;
  uint64_t wr[9 * W];
  const uint64_t* wg = wt + (long)co * (9 * W);
#pragma unroll
  for (int i = 0; i < 9 * W; i++) wr[i] = wg[i];
  __syncthreads();
  int py = chunk * 4 + slot;
  if (py >= PH) return;
  float alpha = cp[0];
  const int K = 9 * 64 * W;
  const uint64_t* base = &sIn[(2 * slot) * (IH * W)];  // local row = 2*slot+cy
  uint64_t c[4][2 * W];
#pragma unroll
  for (int cy = 0; cy < 4; cy++) {
    const uint64_t* p = &base[(cy * IH) * W];
#pragma unroll
    for (int j = 0; j < 2 * W; j++) c[cy][j] = p[j];
  }
#pragma unroll
  for (int px = 0; px < PH; px++) {
    int a00 = 0, a01 = 0, a10 = 0, a11 = 0;
#pragma unroll
    for (int cy = 0; cy < 4; cy++) {
      uint64_t f[2 * W];
      const uint64_t* fp = &base[(cy * IH + 2 * px + 2) * W];
#pragma unroll
      for (int j = 0; j < 2 * W; j++) f[j] = fp[j];
#pragma unroll
      for (int col = 0; col < 4; col++) {
#pragma unroll
        for (int wd = 0; wd < W; wd++) {
          uint64_t v = (col < 2) ? c[cy][col * W + wd] : f[(col - 2) * W + wd];
#pragma unroll
          for (int dy = 0; dy < 2; dy++) {
            int ky = cy - dy;
            if (ky < 0 || ky > 2) continue;  // compile-time folded
#pragma unroll
            for (int dx = 0; dx < 2; dx++) {
              int kx = col - dx;
              if (kx < 0 || kx > 2) continue;  // compile-time folded
              int p = __popcll(v ^ wr[(ky * 3 + kx) * W + wd]);
              if (dy == 0) { if (dx == 0) a00 += p; else a01 += p; }
              else         { if (dx == 0) a10 += p; else a11 += p; }
            }
          }
        }
      }
#pragma unroll
      for (int j = 0; j < 2 * W; j++) c[cy][j] = f[j];
    }
    int dot = K - 2 * min(min(a00, a01), min(a10, a11));
    float f = (float)dot;
    long idx = CL ? (((long)n * PH * PH + py * PH + px) * CO + co)
                  : (((long)n * CO + co) * PH * PH + (py * PH + px));
    out[idx] = dot >= 0 ? f : alpha * f;
  }
}

// conv3 = R4's convs3 (kept): half-wave split, NAMED scalar weights only,
// no scratch (R4: FETCH 2.5MB). W=4 arrays cannot stay in registers (R3:
// 682MB scratch traffic), so the half-wave form is the right one here.
#define TAP2(acc, P, wa, wb) acc += __popcll((P).x ^ (wa)) + __popcll((P).y ^ (wb));
#define ROWT(aL, aR, pA, pB, pC, pD, WX, WY, WZ)                \
  TAP2(aL, pA, WX.x, WX.y) TAP2(aL, pB, WY.x, WY.y)             \
  TAP2(aL, pC, WZ.x, WZ.y)                                      \
  TAP2(aR, pB, WX.x, WX.y) TAP2(aR, pC, WY.x, WY.y)             \
  TAP2(aR, pD, WZ.x, WZ.y)

__global__ __attribute__((amdgpu_flat_work_group_size(256, 256),
                          amdgpu_waves_per_eu(4, 6)))
void convs3(const uint64_t* __restrict__ in, const uint64_t* __restrict__ wt,
            const float* __restrict__ cp, float* __restrict__ out) {
  __shared__ uint64_t sIn[14 * 14 * 4];
  int n = blockIdx.y, cg = blockIdx.x;
  int t = threadIdx.x, lane = t & 63, slot = t >> 6;
  const uint64_t* src = in + (long)n * 784;
  for (int i = t; i < 784; i += 256) sIn[i] = src[i];
  int h = lane >> 5;
  int co = cg * 32 + (lane & 31);
  const uint64_t* wg = wt + co * 36 + 2 * h;
  ulonglong2 W0 = *(const ulonglong2*)(wg + 0);
  ulonglong2 W1 = *(const ulonglong2*)(wg + 4);
  ulonglong2 W2 = *(const ulonglong2*)(wg + 8);
  ulonglong2 W3 = *(const ulonglong2*)(wg + 12);
  ulonglong2 W4 = *(const ulonglong2*)(wg + 16);
  ulonglong2 W5 = *(const ulonglong2*)(wg + 20);
  ulonglong2 W6 = *(const ulonglong2*)(wg + 24);
  ulonglong2 W7 = *(const ulonglong2*)(wg + 28);
  ulonglong2 W8 = *(const ulonglong2*)(wg + 32);
  __syncthreads();
  float alpha = cp[0];
  float* outb = out + ((long)n * 512 + co) * 36;
#pragma unroll
  for (int k = 0; k < 9; k++) {
    int pos = slot + 4 * k;  // 0..35
    int py = pos / 6, px = pos - py * 6;
    const uint64_t* q = sIn + ((2 * py) * 14 + 2 * px) * 4 + 2 * h;
    int a00 = 0, a01 = 0, a10 = 0, a11 = 0;
    {
      ulonglong2 p0 = *(const ulonglong2*)(q + 0);
      ulonglong2 p1 = *(const ulonglong2*)(q + 4);
      ulonglong2 p2 = *(const ulonglong2*)(q + 8);
      ulonglong2 p3 = *(const ulonglong2*)(q + 12);
      ROWT(a00, a01, p0, p1, p2, p3, W0, W1, W2)
    }
    {
      const uint64_t* q1 = q + 56;
      ulonglong2 p0 = *(const ulonglong2*)(q1 + 0);
      ulonglong2 p1 = *(const ulonglong2*)(q1 + 4);
      ulonglong2 p2 = *(const ulonglong2*)(q1 + 8);
      ulonglong2 p3 = *(const ulonglong2*)(q1 + 12);
      ROWT(a00, a01, p0, p1, p2, p3, W3, W4, W5)
      ROWT(a10, a11, p0, p1, p2, p3, W0, W1, W2)
    }
    {
      const uint64_t* q2 = q + 112;
      ulonglong2 p0 = *(const ulonglong2*)(q2 + 0);
      ulonglong2 p1 = *(const ulonglong2*)(q2 + 4);
      ulonglong2 p2 = *(const ulonglong2*)(q2 + 8);
      ulonglong2 p3 = *(const ulonglong2*)(q2 + 12);
      ROWT(a00, a01, p0, p1, p2, p3, W6, W7, W8)
      ROWT(a10, a11, p0, p1, p2, p3, W3, W4, W5)
    }
    {
      const uint64_t* q3 = q + 168;
      ulonglong2 p0 = *(const ulonglong2*)(q3 + 0);
      ulonglong2 p1 = *(const ulonglong2*)(q3 + 4);
      ulonglong2 p2 = *(const ulonglong2*)(q3 + 8);
      ulonglong2 p3 = *(const ulonglong2*)(q3 + 12);
      ROWT(a10, a11, p0, p1, p2, p3, W6, W7, W8)
    }
    int t00 = a00 + __shfl_xor(a00, 32);
    int t01 = a01 + __shfl_xor(a01, 32);
    int t10 = a10 + __shfl_xor(a10, 32);
    int t11 = a11 + __shfl_xor(a11, 32);
    if (h == 0) {
      int dot = 2304 - 2 * min(min(t00, t01), min(t10, t11));
      float ff = (float)dot;
      outb[pos] = dot >= 0 ? ff : alpha * ff;
    }
  }
}

// ---------------- binary fc (with nonzero mask on activations) ----------------

__global__ void fc_bin2(const uint64_t* __restrict__ xp, const uint64_t* __restrict__ wp_t,
                        const float* __restrict__ cp, float* __restrict__ out,
                        int O, int Wf) {
  __shared__ uint64_t xs[2][288], xz[2][288];
  int r0 = blockIdx.y * 2;
  for (int i = threadIdx.x; i < 2 * Wf; i += blockDim.x) {
    int rr = i / Wf, wd = i - rr * Wf;
    xs[rr][wd] = xp[(((long)(r0 + rr)) * Wf + wd) * 2];
    xz[rr][wd] = xp[(((long)(r0 + rr)) * Wf + wd) * 2 + 1];
  }
  __syncthreads();
  int o = blockIdx.x * blockDim.x + threadIdx.x;
  if (o >= O) return;
  int pc0 = 0, pc1 = 0, nz0 = 0, nz1 = 0;
  for (int wd = 0; wd < Wf; wd++) {
    uint64_t w = wp_t[(long)wd * O + o];
    uint64_t z0 = xz[0][wd], z1 = xz[1][wd];
    pc0 += __popcll((xs[0][wd] ^ w) & z0);
    pc1 += __popcll((xs[1][wd] ^ w) & z1);
    nz0 += __popcll(z0);
    nz1 += __popcll(z1);
  }
  float alpha = cp[0];
  int d0 = nz0 - 2 * pc0, d1 = nz1 - 2 * pc1;
  float f0 = (float)d0, f1 = (float)d1;
  out[(long)r0 * O + o] = d0 >= 0 ? f0 : alpha * f0;
  out[(long)(r0 + 1) * O + o] = d1 >= 0 ? f1 : alpha * f1;
}

__global__ void fc_bin_scale(const uint64_t* __restrict__ xp, const uint64_t* __restrict__ wp_t,
                             const float* __restrict__ cp, const float* __restrict__ scale,
                             float* __restrict__ out, int R, int O, int Wf) {
  int i = blockIdx.x * blockDim.x + threadIdx.x;
  if (i >= R * O) return;
  int o = i % O, r = i / O;
  int pc = 0, nzc = 0;
  for (int wd = 0; wd < Wf; wd++) {
    uint64_t nz = xp[((long)r * Wf + wd) * 2 + 1];
    pc += __popcll((xp[((long)r * Wf + wd) * 2] ^ wp_t[(long)wd * O + o]) & nz);
    nzc += __popcll(nz);
  }
  int dot = nzc - 2 * pc;
  float f = (float)dot;
  float alpha = cp[0];
  f = dot >= 0 ? f : alpha * f;
  out[i] = f * scale[0];
}

// ---------------- launch ----------------

extern "C" void kernel_launch(void* const* d_in, const int* in_sizes, int n_in,
                              void* d_out, int out_size, void* d_ws, size_t ws_size,
                              hipStream_t stream) {
  const float* x   = (const float*)d_in[0];
  const float* cg0 = (const float*)d_in[1];
  const float* cb0 = (const float*)d_in[2];
  const float* cw0 = (const float*)d_in[3];
  const float* cp0 = (const float*)d_in[4];
  const float* cg1 = (const float*)d_in[5];
  const float* cb1 = (const float*)d_in[6];
  const float* cw1 = (const float*)d_in[7];
  const float* cp1 = (const float*)d_in[8];
  const float* cg2 = (const float*)d_in[9];
  const float* cb2 = (const float*)d_in[10];
  const float* cw2 = (const float*)d_in[11];
  const float* cp2 = (const float*)d_in[12];
  const float* fg0 = (const float*)d_in[13];
  const float* fb0 = (const float*)d_in[14];
  const float* fw0 = (const float*)d_in[15];
  const float* fp0 = (const float*)d_in[16];
  const float* fg1 = (const float*)d_in[17];
  const float* fb1 = (const float*)d_in[18];
  const float* fw1 = (const float*)d_in[19];
  const float* fp1 = (const float*)d_in[20];
  const float* scl = (const float*)d_in[21];

  char* ws = (char*)d_ws;
  size_t off = 0;
  auto alloc = [&](size_t bytes) {
    size_t r = off;
    off += (bytes + 255) & ~(size_t)255;
    return r;
  };
  const int C0_OFF = 0, C1_OFF = 16, C2_OFF = 160, C3_OFF = 448, C4_OFF = 18944;
  const int NCH = 19968;

  double*   sums  = (double*)(ws + alloc((size_t)NCH * 2 * sizeof(double)));
  double2*  stats = (double2*)(ws + alloc((size_t)NCH * sizeof(double2)));
  double*   parts = (double*)(ws + alloc(512L * 512 * sizeof(double)));  // 2-stage partials
  double*   pplane= (double*)(ws + alloc(128L * 3 * 2 * sizeof(double)));
  uint64_t* rows0 = (uint64_t*)(ws + alloc(128L * 3 * 64 * 8));
  uint32_t* wm1   = (uint32_t*)(ws + alloc(128L * 4));
  float*    a1    = (float*)(ws + alloc(128L * 961 * 128 * 4));   // channel-last
  uint64_t* s1p   = (uint64_t*)(ws + alloc(128L * 961 * 2 * 8));
  uint64_t* w1p   = (uint64_t*)(ws + alloc(256L * 9 * 2 * 8));
  float*    a2    = (float*)(ws + alloc(128L * 196 * 256 * 4));   // channel-last
  uint64_t* s2p   = (uint64_t*)(ws + alloc(128L * 196 * 4 * 8));
  uint64_t* w2p   = (uint64_t*)(ws + alloc(512L * 9 * 4 * 8));
  float*    a3    = (float*)(ws + alloc(128L * 512 * 36 * 4));    // channel-major (reshape order)
  uint64_t* s3p   = (uint64_t*)(ws + alloc(128L * 288 * 2 * 8));
  uint64_t* w3p   = (uint64_t*)(ws + alloc(1024L * 288 * 8));     // transposed [288][1024]
  float*    f1    = (float*)(ws + alloc(128L * 1024 * 4));
  uint64_t* s4p   = (uint64_t*)(ws + alloc(128L * 16 * 2 * 8));
  uint64_t* w4p   = (uint64_t*)(ws + alloc(10L * 16 * 8));        // transposed [16][10]

  const int B = 256;

  // only the fc-stat atomic regions (C3,C4) need zeroing now
  zero_d<<<dim3(153), B, 0, stream>>>(sums + 2 * C3_OFF, (NCH - C3_OFF) * 2);

  // ---- block 0: BN(x) -> sign-bits -> conv1(popcount) -> pool -> prelu ----
  reduce_plane_p<<<dim3(3, 128), B, 0, stream>>>(x, pplane, 3, 4096);
  finalize_plane_par<<<dim3(3), 128, 0, stream>>>(pplane, stats + C0_OFF, 3, 128, 524288.0);
  pack_bits_c1<<<dim3(768), B, 0, stream>>>(x, stats + C0_OFF, cg0, cb0, rows0, 24576);
  pack_wc1<<<1, 128, 0, stream>>>(cw0, wm1);
  conv1_pool3<<<dim3(16, 128), B, 0, stream>>>(rows0, wm1, cp0, a1);

  // ---- block 1: BN(a1) -> pack -> conv2 -> pool -> prelu ----
  reduce_cl_p<<<dim3(2, 512), B, 0, stream>>>(a1, parts, 128, 123008L);
  finalize_parts_par<<<dim3(128), B, 0, stream>>>(parts, stats + C1_OFF, 128, 512, 123008.0);
  pack_cl<<<dim3(7688), B, 0, stream>>>(a1, stats + C1_OFF, cg1, cb1, s1p, 128, 246016L, 1);
  pack_wconv<<<dim3(18), B, 0, stream>>>(cw1, w1p, 256, 128, 2);
  // 4 co-groups x 4 py-chunks
  convp_carry<2, 31, 14, 4, true><<<dim3(16, 128), B, 0, stream>>>(s1p, w1p, cp1, a2, 256);

  // ---- block 2: BN(a2) -> pack -> conv3 -> pool -> prelu ----
  reduce_cl_p<<<dim3(4, 256), B, 0, stream>>>(a2, parts, 256, 25088L);
  finalize_parts_par<<<dim3(256), B, 0, stream>>>(parts, stats + C2_OFF, 256, 256, 25088.0);
  pack_cl<<<dim3(3136), B, 0, stream>>>(a2, stats + C2_OFF, cg2, cb2, s2p, 256, 100352L, 2);
  pack_wconv<<<dim3(72), B, 0, stream>>>(cw2, w2p, 512, 256, 4);
  // 16 co-groups (32 co each)
  convs3<<<dim3(16, 128), B, 0, stream>>>(s2p, w2p, cp2, a3);

  // ---- fc 0: BN1d -> sign @ sign(W).T -> prelu ----
  reduce_cols2<<<dim3(72, 8), B, 0, stream>>>(a3, sums + 2 * C3_OFF, 128, 18432, 16);
  finalize_stats<<<dim3(72), B, 0, stream>>>(sums + 2 * C3_OFF, stats + C3_OFF, 18432, 128.0);
  pack_nz<<<dim3(1152), B, 0, stream>>>(a3, stats + C3_OFF, fg0, fb0, s3p, 128, 18432);
  pack_wfc2_t<<<dim3(9216), B, 0, stream>>>(fw0, w3p, 1024, 18432);
  fc_bin2<<<dim3(4, 64), B, 0, stream>>>(s3p, w3p, fp0, f1, 1024, 288);

  // ---- fc 1: BN1d -> sign @ sign(W).T -> prelu -> scale ----
  reduce_cols2<<<dim3(4, 8), B, 0, stream>>>(f1, sums + 2 * C4_OFF, 128, 1024, 16);
  finalize_stats<<<dim3(4), B, 0, stream>>>(sums + 2 * C4_OFF, stats + C4_OFF, 1024, 128.0);
  pack_nz<<<dim3(64), B, 0, stream>>>(f1, stats + C4_OFF, fg1, fb1, s4p, 128, 1024);
  pack_wfc2_t<<<dim3(5), B, 0, stream>>>(fw1, w4p, 10, 1024);
  fc_bin_scale<<<dim3(5), B, 0, stream>>>(s4p, w4p, fp1, scl, (float*)d_out, 128, 10, 16);
}

// Round 9
// 494.745 us; speedup vs baseline: 1.4286x; 1.0346x over previous
//
#include <hip/hip_runtime.h>
#include <cstdint>
#include <cstddef>

#define BN_EPS 1e-5

// ---------------- reductions ----------------
// R8: conv BN-stats are FUSED into the conv epilogues (per-thread fp64
// s/s2 of prelu(dot) — exact on the quarter-int lattice, order-free),
// written as per-block partials and finalized by parallel per-channel
// kernels. No deep atomics (R2: ~320ns/serialized RMW), no serial
// single-wave finalize (R6: 126us tail), no separate reduce pass over
// the activation tensor.

__global__ void zero_d(double* p, int n) {
  int i = blockIdx.x * blockDim.x + threadIdx.x;
  if (i < n) p[i] = 0.0;
}

// one contiguous HW plane per block: grid (C, N); partial per (c,n)
__global__ void reduce_plane_p(const float* __restrict__ x, double* __restrict__ pp,
                               int C, int HW) {
  int c = blockIdx.x, n = blockIdx.y;
  const float* p = x + ((long)n * C + c) * HW;
  double s = 0.0, s2 = 0.0;
  for (int i = threadIdx.x; i < HW; i += blockDim.x) {
    double v = (double)p[i];
    s += v; s2 += v * v;
  }
  for (int o = 32; o > 0; o >>= 1) {
    s  += __shfl_down(s, o, 64);
    s2 += __shfl_down(s2, o, 64);
  }
  __shared__ double ls[4], ls2[4];
  int lane = threadIdx.x & 63, w = threadIdx.x >> 6;
  if (lane == 0) { ls[w] = s; ls2[w] = s2; }
  __syncthreads();
  if (threadIdx.x == 0) {
    double a = 0, b = 0;
    for (int i = 0; i < 4; i++) { a += ls[i]; b += ls2[i]; }
    long o = ((long)n * C + c) * 2;
    pp[o] = a; pp[o + 1] = b;
  }
}

__global__ void finalize_plane_par(const double* __restrict__ pp, double2* __restrict__ st,
                                   int C, int N, double cnt) {
  int c = blockIdx.x;
  double s = 0.0, s2 = 0.0;
  for (int n = threadIdx.x; n < N; n += blockDim.x) {
    long o = ((long)n * C + c) * 2;
    s  += pp[o];
    s2 += pp[o + 1];
  }
  for (int o = 32; o > 0; o >>= 1) {
    s  += __shfl_down(s, o, 64);
    s2 += __shfl_down(s2, o, 64);
  }
  __shared__ double ls[2], ls2[2];
  int lane = threadIdx.x & 63, w = threadIdx.x >> 6;
  if (lane == 0) { ls[w] = s; ls2[w] = s2; }
  __syncthreads();
  if (threadIdx.x == 0) {
    double a = ls[0] + ls[1], b = ls2[0] + ls2[1];
    double m = a / cnt;
    double v = b / cnt - m * m;
    st[c] = make_double2(m, 1.0 / sqrt(v + BN_EPS));
  }
}

// finalize conv-fused partials, layout pp[y][C]: block per channel.
__global__ void finalize_pp1(const double2* __restrict__ pp, double2* __restrict__ st,
                             int C, int Y, double cnt) {
  int c = blockIdx.x;
  double s = 0.0, s2 = 0.0;
  for (int y = threadIdx.x; y < Y; y += blockDim.x) {
    double2 p = pp[(long)y * C + c];
    s += p.x; s2 += p.y;
  }
  for (int o = 32; o > 0; o >>= 1) {
    s  += __shfl_down(s, o, 64);
    s2 += __shfl_down(s2, o, 64);
  }
  __shared__ double ls[4], ls2[4];
  int lane = threadIdx.x & 63, w = threadIdx.x >> 6;
  if (lane == 0) { ls[w] = s; ls2[w] = s2; }
  __syncthreads();
  if (threadIdx.x == 0) {
    double a = ls[0] + ls[1] + ls[2] + ls[3];
    double b = ls2[0] + ls2[1] + ls2[2] + ls2[3];
    double m = a / cnt;
    double v = b / cnt - m * m;
    st[c] = make_double2(m, 1.0 / sqrt(v + BN_EPS));
  }
}

// finalize conv2 partials: pp[bid][64] with bid = n*16 + (cg*4+chunk).
// channel c: cg=c>>6, l=c&63; y enumerates (n,chunk) 512 combos.
__global__ void finalize_pp2(const double2* __restrict__ pp, double2* __restrict__ st,
                             double cnt) {
  int c = blockIdx.x;
  int cg = c >> 6, l = c & 63;
  double s = 0.0, s2 = 0.0;
  for (int y = threadIdx.x; y < 512; y += blockDim.x) {
    int n = y >> 2, ch = y & 3;
    double2 p = pp[(long)(n * 16 + cg * 4 + ch) * 64 + l];
    s += p.x; s2 += p.y;
  }
  for (int o = 32; o > 0; o >>= 1) {
    s  += __shfl_down(s, o, 64);
    s2 += __shfl_down(s2, o, 64);
  }
  __shared__ double ls[4], ls2[4];
  int lane = threadIdx.x & 63, w = threadIdx.x >> 6;
  if (lane == 0) { ls[w] = s; ls2[w] = s2; }
  __syncthreads();
  if (threadIdx.x == 0) {
    double a = ls[0] + ls[1] + ls[2] + ls[3];
    double b = ls2[0] + ls2[1] + ls2[2] + ls2[3];
    double m = a / cnt;
    double v = b / cnt - m * m;
    st[c] = make_double2(m, 1.0 / sqrt(v + BN_EPS));
  }
}

// per-feature reduce of a3 (i16 dots): R x F, prelu applied inline.
// depth-8 atomics (~2.5us) — acceptable.
__global__ void reduce_cols2_i16(const short* __restrict__ x, const float* __restrict__ cp,
                                 double* __restrict__ sums, int R, int F, int RS) {
  int f = blockIdx.x * blockDim.x + threadIdx.x;
  int r0 = blockIdx.y * RS, r1 = min(r0 + RS, R);
  float alpha = cp[0];
  double s = 0.0, s2 = 0.0;
  for (int r = r0; r < r1; r++) {
    int xi = x[(long)r * F + f];
    float pr = xi >= 0 ? (float)xi : alpha * (float)xi;
    double v = (double)pr;
    s += v; s2 += v * v;
  }
  atomicAdd(&sums[2 * f], s);
  atomicAdd(&sums[2 * f + 1], s2);
}

__global__ void reduce_cols2(const float* __restrict__ x, double* __restrict__ sums,
                             int R, int F, int RS) {
  int f = blockIdx.x * blockDim.x + threadIdx.x;
  int r0 = blockIdx.y * RS, r1 = min(r0 + RS, R);
  double s = 0.0, s2 = 0.0;
  for (int r = r0; r < r1; r++) {
    double v = (double)x[(long)r * F + f];
    s += v; s2 += v * v;
  }
  atomicAdd(&sums[2 * f], s);
  atomicAdd(&sums[2 * f + 1], s2);
}

__global__ void finalize_stats(const double* __restrict__ sums, double2* __restrict__ st,
                               int C, double cnt) {
  int c = blockIdx.x * blockDim.x + threadIdx.x;
  if (c >= C) return;
  double m = sums[2 * c] / cnt;
  double v = sums[2 * c + 1] / cnt - m * m;
  st[c] = make_double2(m, 1.0 / sqrt(v + BN_EPS));
}

// ---------------- ballot-based sign/pack kernels ----------------

__global__ void pack_bits_c1(const float* __restrict__ x, const double2* __restrict__ st,
                             const float* __restrict__ g, const float* __restrict__ b,
                             uint64_t* __restrict__ rows, int nwid) {
  long base = ((long)blockIdx.x * 4 + (threadIdx.x >> 6)) * 8;
  int lane = threadIdx.x & 63;
  for (int j = 0; j < 8; j++) {
    long wid = base + j;
    if (wid >= nwid) return;
    int n = (int)(wid / 192), rem = (int)(wid % 192);
    int ci = rem >> 6, y = rem & 63;
    double2 s = st[ci];
    float xv = x[(((long)n * 3 + ci) * 64 + y) * 64 + lane];
    float xn = (float)(((double)xv - s.x) * s.y) * g[ci] + b[ci];
    uint64_t m = __ballot(xn > 0.f);
    if (lane == 0) rows[wid] = m;
  }
}

__global__ void pack_wc1(const float* __restrict__ w, uint32_t* __restrict__ wm) {
  int co = threadIdx.x;
  uint32_t m = 0;
  for (int j = 0; j < 27; j++) m |= (uint32_t)(w[co * 27 + j] > 0.f) << j;
  wm[co] = m;
}

// pack from i8 dots: v = prelu(dot) then BN sign.
__global__ void pack_cl_i8(const signed char* __restrict__ acl, const double2* __restrict__ st,
                           const float* __restrict__ g, const float* __restrict__ b,
                           const float* __restrict__ cp, uint64_t* __restrict__ out,
                           int C, long nwords, int lw) {
  long base = ((long)blockIdx.x * 4 + (threadIdx.x >> 6)) * 8;
  int lane = threadIdx.x & 63;
  float alpha = cp[0];
  for (int j = 0; j < 8; j++) {
    long wid = base + j;
    if (wid >= nwords) return;
    long row = wid >> lw;
    int w = (int)(wid & ((1 << lw) - 1));
    int c = w * 64 + lane;
    double2 s = st[c];
    int xi = acl[row * C + c];
    float pr = xi >= 0 ? (float)xi : alpha * (float)xi;
    float xn = (float)(((double)pr - s.x) * s.y) * g[c] + b[c];
    uint64_t m = __ballot(xn > 0.f);
    if (lane == 0) out[wid] = m;
  }
}

__global__ void pack_cl_i16(const short* __restrict__ acl, const double2* __restrict__ st,
                            const float* __restrict__ g, const float* __restrict__ b,
                            const float* __restrict__ cp, uint64_t* __restrict__ out,
                            int C, long nwords, int lw) {
  long base = ((long)blockIdx.x * 4 + (threadIdx.x >> 6)) * 8;
  int lane = threadIdx.x & 63;
  float alpha = cp[0];
  for (int j = 0; j < 8; j++) {
    long wid = base + j;
    if (wid >= nwords) return;
    long row = wid >> lw;
    int w = (int)(wid & ((1 << lw) - 1));
    int c = w * 64 + lane;
    double2 s = st[c];
    int xi = acl[row * C + c];
    float pr = xi >= 0 ? (float)xi : alpha * (float)xi;
    float xn = (float)(((double)pr - s.x) * s.y) * g[c] + b[c];
    uint64_t m = __ballot(xn > 0.f);
    if (lane == 0) out[wid] = m;
  }
}

__global__ void pack_wconv(const float* __restrict__ w, uint64_t* __restrict__ out,
                           int CO, int CI, int W) {
  int i = blockIdx.x * blockDim.x + threadIdx.x;
  int total = CO * 9 * W;
  if (i >= total) return;
  int wd = i % W;
  int t = i / W;
  int tap = t % 9, co = t / 9;
  uint64_t bits = 0;
  for (int k = 0; k < 64; k++) {
    int ci = wd * 64 + k;
    bits |= (uint64_t)(w[((long)co * CI + ci) * 9 + tap] > 0.f) << k;
  }
  out[i] = bits;
}

// pack sign + nonzero masks from i16 dots (a3); nzc recomputed inline in fc.
__global__ void pack_nz_i16(const short* __restrict__ x, const double2* __restrict__ st,
                            const float* __restrict__ g, const float* __restrict__ b,
                            const float* __restrict__ cp, uint64_t* __restrict__ out,
                            int R, int F) {
  int Wf = F >> 6;
  long base = ((long)blockIdx.x * 4 + (threadIdx.x >> 6)) * 8;
  int lane = threadIdx.x & 63;
  float alpha = cp[0];
  for (int j = 0; j < 8; j++) {
    long wid = base + j;
    if (wid >= (long)R * Wf) return;
    long r = wid / Wf;
    int w = (int)(wid % Wf);
    int f = w * 64 + lane;
    double2 s = st[f];
    int xi = x[r * F + f];
    float pr = xi >= 0 ? (float)xi : alpha * (float)xi;
    double d = (double)pr - s.x;  // exact for lattice values
    float xn = (float)(d * s.y) * g[f] + b[f];
    uint64_t sm = __ballot(xn > 0.f);
    uint64_t nm = __ballot(d != 0.0);
    if (lane == 0) { out[2 * wid] = sm; out[2 * wid + 1] = nm; }
  }
}

__global__ void pack_nz(const float* __restrict__ x, const double2* __restrict__ st,
                        const float* __restrict__ g, const float* __restrict__ b,
                        uint64_t* __restrict__ out, int R, int F) {
  int Wf = F >> 6;
  long base = ((long)blockIdx.x * 4 + (threadIdx.x >> 6)) * 8;
  int lane = threadIdx.x & 63;
  for (int j = 0; j < 8; j++) {
    long wid = base + j;
    if (wid >= (long)R * Wf) return;
    long r = wid / Wf;
    int w = (int)(wid % Wf);
    int f = w * 64 + lane;
    double2 s = st[f];
    double d = (double)x[r * F + f] - s.x;
    float xn = (float)(d * s.y) * g[f] + b[f];
    uint64_t sm = __ballot(xn > 0.f);
    uint64_t nm = __ballot(d != 0.0);
    if (lane == 0) { out[2 * wid] = sm; out[2 * wid + 1] = nm; }
  }
}

// transposed weight pack: out [wd][O] so fc weight loads are lane-coalesced
__global__ void pack_wfc2_t(const float* __restrict__ w, uint64_t* __restrict__ out,
                            int O, int F) {
  int Wf = F >> 6;
  long base = ((long)blockIdx.x * 4 + (threadIdx.x >> 6)) * 8;
  int lane = threadIdx.x & 63;
  for (int j = 0; j < 8; j++) {
    long wid = base + j;
    if (wid >= (long)O * Wf) return;
    long o = wid / Wf;
    int wd = (int)(wid % Wf);
    uint64_t m = __ballot(w[o * F + wd * 64 + lane] > 0.f);
    if (lane == 0) out[(long)wd * O + o] = m;
  }
}

// ---------------- fused conv + maxpool + prelu (+ BN stats) ----------------

// conv1: i8 dot output channel-last [n][961][128] + fused per-block stats.
__global__ __launch_bounds__(256) void conv1_pool3_i8(const uint64_t* __restrict__ rows,
                                                      const uint32_t* __restrict__ wm,
                                                      const float* __restrict__ cp,
                                                      signed char* __restrict__ out,
                                                      double2* __restrict__ pp) {
  __shared__ uint64_t rL[192];
  __shared__ uint32_t wL[128];
  __shared__ uint32_t mL[61 * 4];
  __shared__ double2 sm[256];
  int n = blockIdx.y, chunk = blockIdx.x, t = threadIdx.x;
  if (t < 192) rL[t] = rows[n * 192 + t];
  if (t < 128) wL[t] = wm[t];
  __syncthreads();
  if (t < 244) {
    int pl = t >> 2, quad = t & 3;
    int pos = chunk * 61 + pl;
    if (pos < 961) {
      int py = pos / 31, px = pos - py * 31;
      int cy = 2 * py + (quad >> 1), cx = 2 * px + (quad & 1);
      uint32_t m = 0;
#pragma unroll
      for (int ci = 0; ci < 3; ci++)
#pragma unroll
        for (int ky = 0; ky < 3; ky++)
          m |= (uint32_t)((rL[ci * 64 + cy + ky] >> cx) & 7) << (ci * 9 + ky * 3);
      mL[pl * 4 + quad] = m;
    }
  }
  __syncthreads();
  int co = t & 127, slot = t >> 7;
  float alpha = cp[0];
  uint32_t w = wL[co];
  double s = 0.0, s2 = 0.0;
  for (int i = slot; i < 61; i += 2) {
    int pos = chunk * 61 + i;
    if (pos >= 961) break;
    int p0 = __popc(mL[4 * i] ^ w);
    int p1 = __popc(mL[4 * i + 1] ^ w);
    int p2 = __popc(mL[4 * i + 2] ^ w);
    int p3 = __popc(mL[4 * i + 3] ^ w);
    int dot = 27 - 2 * min(min(p0, p1), min(p2, p3));
    out[((long)n * 961 + pos) * 128 + co] = (signed char)dot;
    float pr = dot >= 0 ? (float)dot : alpha * (float)dot;
    double v = (double)pr;
    s += v; s2 += v * v;
  }
  sm[t] = make_double2(s, s2);
  __syncthreads();
  if (t < 128) {
    double2 a = sm[t], b = sm[t + 128];
    pp[((long)n * 16 + chunk) * 128 + t] = make_double2(a.x + b.x, a.y + b.y);
  }
}

// conv2 (R7 convp_carry core, I/O changed): i16 dot output CL [n][196][256]
// + fused stats. No early return (divergent-barrier safe): inactive waves
// contribute zero partials.
template <int W, int IH, int PH, int CHUNK>
__global__ __attribute__((amdgpu_flat_work_group_size(256, 256),
                          amdgpu_waves_per_eu(3, 4)))
void convp_carry_i16(const uint64_t* __restrict__ in, const uint64_t* __restrict__ wt,
                     const float* __restrict__ cp, short* __restrict__ out,
                     double2* __restrict__ pp, int CO) {
  __shared__ uint64_t sIn[10 * IH * W];
  __shared__ double2 sm[256];
  int n = blockIdx.y;
  int cg = blockIdx.x / CHUNK, chunk = blockIdx.x % CHUNK;
  int t = threadIdx.x, lane = t & 63, slot = t >> 6;
  int r0 = chunk * 8;
  int nr = min(10, IH - r0);
  const uint64_t* src = in + ((long)n * IH + r0) * (IH * W);
  for (int i = t; i < nr * IH * W; i += 256) sIn[i] = src[i];
  int co = cg * 64 + lane;
  uint64_t wr[9 * W];
  const uint64_t* wg = wt + (long)co * (9 * W);
#pragma unroll
  for (int i = 0; i < 9 * W; i++) wr[i] = wg[i];
  __syncthreads();
  int py = chunk * 4 + slot;
  float alpha = cp[0];
  double s = 0.0, s2 = 0.0;
  if (py < PH) {
    const int K = 9 * 64 * W;
    const uint64_t* base = &sIn[(2 * slot) * (IH * W)];
    uint64_t c[4][2 * W];
#pragma unroll
    for (int cy = 0; cy < 4; cy++) {
      const uint64_t* p = &base[(cy * IH) * W];
#pragma unroll
      for (int j = 0; j < 2 * W; j++) c[cy][j] = p[j];
    }
#pragma unroll
    for (int px = 0; px < PH; px++) {
      int a00 = 0, a01 = 0, a10 = 0, a11 = 0;
#pragma unroll
      for (int cy = 0; cy < 4; cy++) {
        uint64_t f[2 * W];
        const uint64_t* fp = &base[(cy * IH + 2 * px + 2) * W];
#pragma unroll
        for (int j = 0; j < 2 * W; j++) f[j] = fp[j];
#pragma unroll
        for (int col = 0; col < 4; col++) {
#pragma unroll
          for (int wd = 0; wd < W; wd++) {
            uint64_t v = (col < 2) ? c[cy][col * W + wd] : f[(col - 2) * W + wd];
#pragma unroll
            for (int dy = 0; dy < 2; dy++) {
              int ky = cy - dy;
              if (ky < 0 || ky > 2) continue;
#pragma unroll
              for (int dx = 0; dx < 2; dx++) {
                int kx = col - dx;
                if (kx < 0 || kx > 2) continue;
                int p = __popcll(v ^ wr[(ky * 3 + kx) * W + wd]);
                if (dy == 0) { if (dx == 0) a00 += p; else a01 += p; }
                else         { if (dx == 0) a10 += p; else a11 += p; }
              }
            }
          }
        }
#pragma unroll
        for (int j = 0; j < 2 * W; j++) c[cy][j] = f[j];
      }
      int dot = K - 2 * min(min(a00, a01), min(a10, a11));
      out[((long)n * PH * PH + py * PH + px) * CO + co] = (short)dot;
      float pr = dot >= 0 ? (float)dot : alpha * (float)dot;
      double v = (double)pr;
      s += v; s2 += v * v;
    }
  }
  sm[t] = make_double2(s, s2);
  __syncthreads();
  if (t < 64) {
    double2 a = sm[t], b = sm[64 + t], cc = sm[128 + t], d = sm[192 + t];
    pp[((long)blockIdx.y * 16 + blockIdx.x) * 64 + t] =
        make_double2(a.x + b.x + cc.x + d.x, a.y + b.y + cc.y + d.y);
  }
}

// conv3 (R4 convs3 core): i16 dot output channel-major [n][512][36].
// (fc0 BN1d stats are per-FEATURE (co,pos), not per-channel — cannot fuse
// here; reduce_cols2_i16 handles them.)
#define TAP2(acc, P, wa, wb) acc += __popcll((P).x ^ (wa)) + __popcll((P).y ^ (wb));
#define ROWT(aL, aR, pA, pB, pC, pD, WX, WY, WZ)                \
  TAP2(aL, pA, WX.x, WX.y) TAP2(aL, pB, WY.x, WY.y)             \
  TAP2(aL, pC, WZ.x, WZ.y)                                      \
  TAP2(aR, pB, WX.x, WX.y) TAP2(aR, pC, WY.x, WY.y)             \
  TAP2(aR, pD, WZ.x, WZ.y)

__global__ __attribute__((amdgpu_flat_work_group_size(256, 256),
                          amdgpu_waves_per_eu(4, 6)))
void convs3_i16(const uint64_t* __restrict__ in, const uint64_t* __restrict__ wt,
                short* __restrict__ out) {
  __shared__ uint64_t sIn[14 * 14 * 4];
  int n = blockIdx.y, cg = blockIdx.x;
  int t = threadIdx.x, lane = t & 63, slot = t >> 6;
  const uint64_t* src = in + (long)n * 784;
  for (int i = t; i < 784; i += 256) sIn[i] = src[i];
  int h = lane >> 5;
  int co = cg * 32 + (lane & 31);
  const uint64_t* wg = wt + co * 36 + 2 * h;
  ulonglong2 W0 = *(const ulonglong2*)(wg + 0);
  ulonglong2 W1 = *(const ulonglong2*)(wg + 4);
  ulonglong2 W2 = *(const ulonglong2*)(wg + 8);
  ulonglong2 W3 = *(const ulonglong2*)(wg + 12);
  ulonglong2 W4 = *(const ulonglong2*)(wg + 16);
  ulonglong2 W5 = *(const ulonglong2*)(wg + 20);
  ulonglong2 W6 = *(const ulonglong2*)(wg + 24);
  ulonglong2 W7 = *(const ulonglong2*)(wg + 28);
  ulonglong2 W8 = *(const ulonglong2*)(wg + 32);
  __syncthreads();
  short* outb = out + ((long)n * 512 + co) * 36;
#pragma unroll
  for (int k = 0; k < 9; k++) {
    int pos = slot + 4 * k;  // 0..35
    int py = pos / 6, px = pos - py * 6;
    const uint64_t* q = sIn + ((2 * py) * 14 + 2 * px) * 4 + 2 * h;
    int a00 = 0, a01 = 0, a10 = 0, a11 = 0;
    {
      ulonglong2 p0 = *(const ulonglong2*)(q + 0);
      ulonglong2 p1 = *(const ulonglong2*)(q + 4);
      ulonglong2 p2 = *(const ulonglong2*)(q + 8);
      ulonglong2 p3 = *(const ulonglong2*)(q + 12);
      ROWT(a00, a01, p0, p1, p2, p3, W0, W1, W2)
    }
    {
      const uint64_t* q1 = q + 56;
      ulonglong2 p0 = *(const ulonglong2*)(q1 + 0);
      ulonglong2 p1 = *(const ulonglong2*)(q1 + 4);
      ulonglong2 p2 = *(const ulonglong2*)(q1 + 8);
      ulonglong2 p3 = *(const ulonglong2*)(q1 + 12);
      ROWT(a00, a01, p0, p1, p2, p3, W3, W4, W5)
      ROWT(a10, a11, p0, p1, p2, p3, W0, W1, W2)
    }
    {
      const uint64_t* q2 = q + 112;
      ulonglong2 p0 = *(const ulonglong2*)(q2 + 0);
      ulonglong2 p1 = *(const ulonglong2*)(q2 + 4);
      ulonglong2 p2 = *(const ulonglong2*)(q2 + 8);
      ulonglong2 p3 = *(const ulonglong2*)(q2 + 12);
      ROWT(a00, a01, p0, p1, p2, p3, W6, W7, W8)
      ROWT(a10, a11, p0, p1, p2, p3, W3, W4, W5)
    }
    {
      const uint64_t* q3 = q + 168;
      ulonglong2 p0 = *(const ulonglong2*)(q3 + 0);
      ulonglong2 p1 = *(const ulonglong2*)(q3 + 4);
      ulonglong2 p2 = *(const ulonglong2*)(q3 + 8);
      ulonglong2 p3 = *(const ulonglong2*)(q3 + 12);
      ROWT(a10, a11, p0, p1, p2, p3, W6, W7, W8)
    }
    int t00 = a00 + __shfl_xor(a00, 32);
    int t01 = a01 + __shfl_xor(a01, 32);
    int t10 = a10 + __shfl_xor(a10, 32);
    int t11 = a11 + __shfl_xor(a11, 32);
    if (h == 0) {
      int dot = 2304 - 2 * min(min(t00, t01), min(t10, t11));
      outb[pos] = (short)dot;
    }
  }
}

// ---------------- binary fc (with nonzero mask on activations) ----------------

__global__ void fc_bin2(const uint64_t* __restrict__ xp, const uint64_t* __restrict__ wp_t,
                        const float* __restrict__ cp, float* __restrict__ out,
                        int O, int Wf) {
  __shared__ uint64_t xs[2][288], xz[2][288];
  int r0 = blockIdx.y * 2;
  for (int i = threadIdx.x; i < 2 * Wf; i += blockDim.x) {
    int rr = i / Wf, wd = i - rr * Wf;
    xs[rr][wd] = xp[(((long)(r0 + rr)) * Wf + wd) * 2];
    xz[rr][wd] = xp[(((long)(r0 + rr)) * Wf + wd) * 2 + 1];
  }
  __syncthreads();
  int o = blockIdx.x * blockDim.x + threadIdx.x;
  if (o >= O) return;
  int pc0 = 0, pc1 = 0, nz0 = 0, nz1 = 0;
  for (int wd = 0; wd < Wf; wd++) {
    uint64_t w = wp_t[(long)wd * O + o];
    uint64_t z0 = xz[0][wd], z1 = xz[1][wd];
    pc0 += __popcll((xs[0][wd] ^ w) & z0);
    pc1 += __popcll((xs[1][wd] ^ w) & z1);
    nz0 += __popcll(z0);
    nz1 += __popcll(z1);
  }
  float alpha = cp[0];
  int d0 = nz0 - 2 * pc0, d1 = nz1 - 2 * pc1;
  float f0 = (float)d0, f1 = (float)d1;
  out[(long)r0 * O + o] = d0 >= 0 ? f0 : alpha * f0;
  out[(long)(r0 + 1) * O + o] = d1 >= 0 ? f1 : alpha * f1;
}

__global__ void fc_bin_scale(const uint64_t* __restrict__ xp, const uint64_t* __restrict__ wp_t,
                             const float* __restrict__ cp, const float* __restrict__ scale,
                             float* __restrict__ out, int R, int O, int Wf) {
  int i = blockIdx.x * blockDim.x + threadIdx.x;
  if (i >= R * O) return;
  int o = i % O, r = i / O;
  int pc = 0, nzc = 0;
  for (int wd = 0; wd < Wf; wd++) {
    uint64_t nz = xp[((long)r * Wf + wd) * 2 + 1];
    pc += __popcll((xp[((long)r * Wf + wd) * 2] ^ wp_t[(long)wd * O + o]) & nz);
    nzc += __popcll(nz);
  }
  int dot = nzc - 2 * pc;
  float f = (float)dot;
  float alpha = cp[0];
  f = dot >= 0 ? f : alpha * f;
  out[i] = f * scale[0];
}

// ---------------- launch ----------------

extern "C" void kernel_launch(void* const* d_in, const int* in_sizes, int n_in,
                              void* d_out, int out_size, void* d_ws, size_t ws_size,
                              hipStream_t stream) {
  const float* x   = (const float*)d_in[0];
  const float* cg0 = (const float*)d_in[1];
  const float* cb0 = (const float*)d_in[2];
  const float* cw0 = (const float*)d_in[3];
  const float* cp0 = (const float*)d_in[4];
  const float* cg1 = (const float*)d_in[5];
  const float* cb1 = (const float*)d_in[6];
  const float* cw1 = (const float*)d_in[7];
  const float* cp1 = (const float*)d_in[8];
  const float* cg2 = (const float*)d_in[9];
  const float* cb2 = (const float*)d_in[10];
  const float* cw2 = (const float*)d_in[11];
  const float* cp2 = (const float*)d_in[12];
  const float* fg0 = (const float*)d_in[13];
  const float* fb0 = (const float*)d_in[14];
  const float* fw0 = (const float*)d_in[15];
  const float* fp0 = (const float*)d_in[16];
  const float* fg1 = (const float*)d_in[17];
  const float* fb1 = (const float*)d_in[18];
  const float* fw1 = (const float*)d_in[19];
  const float* fp1 = (const float*)d_in[20];
  const float* scl = (const float*)d_in[21];

  char* ws = (char*)d_ws;
  size_t off = 0;
  auto alloc = [&](size_t bytes) {
    size_t r = off;
    off += (bytes + 255) & ~(size_t)255;
    return r;
  };
  const int C0_OFF = 0, C1_OFF = 16, C2_OFF = 160, C3_OFF = 448, C4_OFF = 18944;
  const int NCH = 19968;

  double*   sums  = (double*)(ws + alloc((size_t)NCH * 2 * sizeof(double)));
  double2*  stats = (double2*)(ws + alloc((size_t)NCH * sizeof(double2)));
  double*   pplane= (double*)(ws + alloc(128L * 3 * 2 * sizeof(double)));
  double2*  pp1   = (double2*)(ws + alloc(2048L * 128 * sizeof(double2)));
  double2*  pp2   = (double2*)(ws + alloc(2048L * 64 * sizeof(double2)));
  uint64_t* rows0 = (uint64_t*)(ws + alloc(128L * 3 * 64 * 8));
  uint32_t* wm1   = (uint32_t*)(ws + alloc(128L * 4));
  signed char* a1 = (signed char*)(ws + alloc(128L * 961 * 128));   // i8 dots, CL
  uint64_t* s1p   = (uint64_t*)(ws + alloc(128L * 961 * 2 * 8));
  uint64_t* w1p   = (uint64_t*)(ws + alloc(256L * 9 * 2 * 8));
  short*    a2    = (short*)(ws + alloc(128L * 196 * 256 * 2));     // i16 dots, CL
  uint64_t* s2p   = (uint64_t*)(ws + alloc(128L * 196 * 4 * 8));
  uint64_t* w2p   = (uint64_t*)(ws + alloc(512L * 9 * 4 * 8));
  short*    a3    = (short*)(ws + alloc(128L * 512 * 36 * 2));      // i16 dots, CM
  uint64_t* s3p   = (uint64_t*)(ws + alloc(128L * 288 * 2 * 8));
  uint64_t* w3p   = (uint64_t*)(ws + alloc(1024L * 288 * 8));       // transposed [288][1024]
  float*    f1    = (float*)(ws + alloc(128L * 1024 * 4));
  uint64_t* s4p   = (uint64_t*)(ws + alloc(128L * 16 * 2 * 8));
  uint64_t* w4p   = (uint64_t*)(ws + alloc(10L * 16 * 8));          // transposed [16][10]

  const int B = 256;

  // only the fc-stat atomic regions (C3,C4) need zeroing
  zero_d<<<dim3(153), B, 0, stream>>>(sums + 2 * C3_OFF, (NCH - C3_OFF) * 2);

  // ---- block 0: BN(x) -> sign-bits -> conv1(popcount)+pool+stats ----
  reduce_plane_p<<<dim3(3, 128), B, 0, stream>>>(x, pplane, 3, 4096);
  finalize_plane_par<<<dim3(3), 128, 0, stream>>>(pplane, stats + C0_OFF, 3, 128, 524288.0);
  pack_bits_c1<<<dim3(768), B, 0, stream>>>(x, stats + C0_OFF, cg0, cb0, rows0, 24576);
  pack_wc1<<<1, 128, 0, stream>>>(cw0, wm1);
  conv1_pool3_i8<<<dim3(16, 128), B, 0, stream>>>(rows0, wm1, cp0, a1, pp1);

  // ---- block 1: BN stats from pp1 -> pack -> conv2+stats ----
  finalize_pp1<<<dim3(128), B, 0, stream>>>(pp1, stats + C1_OFF, 128, 2048, 123008.0);
  pack_cl_i8<<<dim3(7688), B, 0, stream>>>(a1, stats + C1_OFF, cg1, cb1, cp0, s1p, 128, 246016L, 1);
  pack_wconv<<<dim3(18), B, 0, stream>>>(cw1, w1p, 256, 128, 2);
  convp_carry_i16<2, 31, 14, 4><<<dim3(16, 128), B, 0, stream>>>(s1p, w1p, cp1, a2, pp2, 256);

  // ---- block 2: BN stats from pp2 -> pack -> conv3 ----
  finalize_pp2<<<dim3(256), B, 0, stream>>>(pp2, stats + C2_OFF, 25088.0);
  pack_cl_i16<<<dim3(3136), B, 0, stream>>>(a2, stats + C2_OFF, cg2, cb2, cp1, s2p, 256, 100352L, 2);
  pack_wconv<<<dim3(72), B, 0, stream>>>(cw2, w2p, 512, 256, 4);
  convs3_i16<<<dim3(16, 128), B, 0, stream>>>(s2p, w2p, a3);

  // ---- fc 0: BN1d (per-feature, atomics) -> sign @ sign(W).T -> prelu ----
  reduce_cols2_i16<<<dim3(72, 8), B, 0, stream>>>(a3, cp2, sums + 2 * C3_OFF, 128, 18432, 16);
  finalize_stats<<<dim3(72), B, 0, stream>>>(sums + 2 * C3_OFF, stats + C3_OFF, 18432, 128.0);
  pack_nz_i16<<<dim3(1152), B, 0, stream>>>(a3, stats + C3_OFF, fg0, fb0, cp2, s3p, 128, 18432);
  pack_wfc2_t<<<dim3(9216), B, 0, stream>>>(fw0, w3p, 1024, 18432);
  fc_bin2<<<dim3(4, 64), B, 0, stream>>>(s3p, w3p, fp0, f1, 1024, 288);

  // ---- fc 1: BN1d -> sign @ sign(W).T -> prelu -> scale ----
  reduce_cols2<<<dim3(4, 8), B, 0, stream>>>(f1, sums + 2 * C4_OFF, 128, 1024, 16);
  finalize_stats<<<dim3(4), B, 0, stream>>>(sums + 2 * C4_OFF, stats + C4_OFF, 1024, 128.0);
  pack_nz<<<dim3(64), B, 0, stream>>>(f1, stats + C4_OFF, fg1, fb1, s4p, 128, 1024);
  pack_wfc2_t<<<dim3(5), B, 0, stream>>>(fw1, w4p, 10, 1024);
  fc_bin_scale<<<dim3(5), B, 0, stream>>>(s4p, w4p, fp1, scl, (float*)d_out, 128, 10, 16);
}

// Round 11
// 455.313 us; speedup vs baseline: 1.5523x; 1.0866x over previous
//
#include <hip/hip_runtime.h>
#include <cstdint>
#include <cstddef>

#define BN_EPS 1e-5

// ---------------- R11 = R10 with pack_weights_all fc0 sizing FIXED ----------------
// R10 failed absmax=0.085: fc0 weight pack covered only 73728 of 294912 words
// (1024 outputs x 288 words). Branch boundaries corrected; all else identical.

// one mega-kernel for all weight packing + zeroing (input-independent).
__global__ void pack_weights_all(const float* __restrict__ cw0, const float* __restrict__ cw1,
                                 const float* __restrict__ cw2, const float* __restrict__ fw0,
                                 const float* __restrict__ fw1,
                                 uint32_t* __restrict__ wm1, uint64_t* __restrict__ w1p,
                                 uint64_t* __restrict__ w2p, uint64_t* __restrict__ w3p,
                                 uint64_t* __restrict__ w4p, double* __restrict__ zp, int zn) {
  int bb = blockIdx.x, t = threadIdx.x, lane = t & 63, wv = t >> 6;
  if (bb == 0) {
    if (t < 128) {
      uint32_t m = 0;
      for (int j = 0; j < 27; j++) m |= (uint32_t)(cw0[t * 27 + j] > 0.f) << j;
      wm1[t] = m;
    }
  } else if (bb < 19) {          // conv2 weights: 256*9*2 = 4608 items
    int i = (bb - 1) * 256 + t;
    if (i < 4608) {
      int wd = i % 2, t2 = i / 2, tap = t2 % 9, co = t2 / 9;
      uint64_t bits = 0;
      for (int k = 0; k < 64; k++)
        bits |= (uint64_t)(cw1[((long)co * 128 + wd * 64 + k) * 9 + tap] > 0.f) << k;
      w1p[i] = bits;
    }
  } else if (bb < 91) {          // conv3 weights: 512*9*4 = 18432 items
    int i = (bb - 19) * 256 + t;
    if (i < 18432) {
      int wd = i % 4, t2 = i / 4, tap = t2 % 9, co = t2 / 9;
      uint64_t bits = 0;
      for (int k = 0; k < 64; k++)
        bits |= (uint64_t)(cw2[((long)co * 256 + wd * 64 + k) * 9 + tap] > 0.f) << k;
      w2p[i] = bits;
    }
  } else if (bb < 9307) {        // fc0 weights transposed: 1024*288 = 294912 wids, 32/block
    long base = ((long)(bb - 91) * 4 + wv) * 8;
    for (int j = 0; j < 8; j++) {
      long wid = base + j;
      if (wid >= 294912) break;
      long o = wid / 288;
      int wd = (int)(wid % 288);
      uint64_t m = __ballot(fw0[o * 18432 + wd * 64 + lane] > 0.f);
      if (lane == 0) w3p[(long)wd * 1024 + o] = m;
    }
  } else if (bb < 9312) {        // fc1 weights transposed: 160 wids
    long base = ((long)(bb - 9307) * 4 + wv) * 8;
    for (int j = 0; j < 8; j++) {
      long wid = base + j;
      if (wid >= 160) break;
      long o = wid / 16;
      int wd = (int)(wid % 16);
      uint64_t m = __ballot(fw1[o * 1024 + wd * 64 + lane] > 0.f);
      if (lane == 0) w4p[(long)wd * 10 + o] = m;
    }
  } else {                       // zero fc0 atomic stats region
    int i = (bb - 9312) * 256 + t;
    if (i < zn) zp[i] = 0.0;
  }
}

// one contiguous HW plane per block: grid (C, N); partial per (c,n)
__global__ void reduce_plane_p(const float* __restrict__ x, double* __restrict__ pp,
                               int C, int HW) {
  int c = blockIdx.x, n = blockIdx.y;
  const float* p = x + ((long)n * C + c) * HW;
  double s = 0.0, s2 = 0.0;
  for (int i = threadIdx.x; i < HW; i += blockDim.x) {
    double v = (double)p[i];
    s += v; s2 += v * v;
  }
  for (int o = 32; o > 0; o >>= 1) {
    s  += __shfl_down(s, o, 64);
    s2 += __shfl_down(s2, o, 64);
  }
  __shared__ double ls[4], ls2[4];
  int lane = threadIdx.x & 63, w = threadIdx.x >> 6;
  if (lane == 0) { ls[w] = s; ls2[w] = s2; }
  __syncthreads();
  if (threadIdx.x == 0) {
    double a = 0, b = 0;
    for (int i = 0; i < 4; i++) { a += ls[i]; b += ls2[i]; }
    long o = ((long)n * C + c) * 2;
    pp[o] = a; pp[o + 1] = b;
  }
}

// pack x signs; finalize_plane fused in-block (pplane is only 768 doubles:
// waves 0..2 each reduce one channel's 128 partials, broadcast via LDS).
__global__ void pack_bits_c1_f(const float* __restrict__ x, const double* __restrict__ pplane,
                               const float* __restrict__ g, const float* __restrict__ b,
                               uint64_t* __restrict__ rows, int nwid) {
  __shared__ double2 stc[3];
  int t = threadIdx.x, lane = t & 63, wv = t >> 6;
  if (wv < 3) {
    int c = wv;
    double s  = pplane[((long)lane * 3 + c) * 2]     + pplane[((long)(lane + 64) * 3 + c) * 2];
    double s2 = pplane[((long)lane * 3 + c) * 2 + 1] + pplane[((long)(lane + 64) * 3 + c) * 2 + 1];
    for (int o = 32; o > 0; o >>= 1) {
      s  += __shfl_down(s, o, 64);
      s2 += __shfl_down(s2, o, 64);
    }
    if (lane == 0) {
      double m = s / 524288.0;
      double v = s2 / 524288.0 - m * m;
      stc[c] = make_double2(m, 1.0 / sqrt(v + BN_EPS));
    }
  }
  __syncthreads();
  long base = ((long)blockIdx.x * 4 + wv) * 8;
  for (int j = 0; j < 8; j++) {
    long wid = base + j;
    if (wid >= nwid) return;
    int n = (int)(wid / 192), rem = (int)(wid % 192);
    int ci = rem >> 6, y = rem & 63;
    double2 s = stc[ci];
    float xv = x[(((long)n * 3 + ci) * 64 + y) * 64 + lane];
    float xn = (float)(((double)xv - s.x) * s.y) * g[ci] + b[ci];
    uint64_t m = __ballot(xn > 0.f);
    if (lane == 0) rows[wid] = m;
  }
}

// finalize conv-fused partials, layout pp[y][C]: block per channel.
__global__ void finalize_pp1(const double2* __restrict__ pp, double2* __restrict__ st,
                             int C, int Y, double cnt) {
  int c = blockIdx.x;
  double s = 0.0, s2 = 0.0;
  for (int y = threadIdx.x; y < Y; y += blockDim.x) {
    double2 p = pp[(long)y * C + c];
    s += p.x; s2 += p.y;
  }
  for (int o = 32; o > 0; o >>= 1) {
    s  += __shfl_down(s, o, 64);
    s2 += __shfl_down(s2, o, 64);
  }
  __shared__ double ls[4], ls2[4];
  int lane = threadIdx.x & 63, w = threadIdx.x >> 6;
  if (lane == 0) { ls[w] = s; ls2[w] = s2; }
  __syncthreads();
  if (threadIdx.x == 0) {
    double a = ls[0] + ls[1] + ls[2] + ls[3];
    double b = ls2[0] + ls2[1] + ls2[2] + ls2[3];
    double m = a / cnt;
    double v = b / cnt - m * m;
    st[c] = make_double2(m, 1.0 / sqrt(v + BN_EPS));
  }
}

// finalize conv2 partials: pp[bid][64] with bid = n*16 + (cg*4+chunk).
__global__ void finalize_pp2(const double2* __restrict__ pp, double2* __restrict__ st,
                             double cnt) {
  int c = blockIdx.x;
  int cg = c >> 6, l = c & 63;
  double s = 0.0, s2 = 0.0;
  for (int y = threadIdx.x; y < 512; y += blockDim.x) {
    int n = y >> 2, ch = y & 3;
    double2 p = pp[(long)(n * 16 + cg * 4 + ch) * 64 + l];
    s += p.x; s2 += p.y;
  }
  for (int o = 32; o > 0; o >>= 1) {
    s  += __shfl_down(s, o, 64);
    s2 += __shfl_down(s2, o, 64);
  }
  __shared__ double ls[4], ls2[4];
  int lane = threadIdx.x & 63, w = threadIdx.x >> 6;
  if (lane == 0) { ls[w] = s; ls2[w] = s2; }
  __syncthreads();
  if (threadIdx.x == 0) {
    double a = ls[0] + ls[1] + ls[2] + ls[3];
    double b = ls2[0] + ls2[1] + ls2[2] + ls2[3];
    double m = a / cnt;
    double v = b / cnt - m * m;
    st[c] = make_double2(m, 1.0 / sqrt(v + BN_EPS));
  }
}

// per-feature reduce of a3 (i16 dots, prelu inline); depth-8 atomics.
__global__ void reduce_cols2_i16(const short* __restrict__ x, const float* __restrict__ cp,
                                 double* __restrict__ sums, int R, int F, int RS) {
  int f = blockIdx.x * blockDim.x + threadIdx.x;
  int r0 = blockIdx.y * RS, r1 = min(r0 + RS, R);
  float alpha = cp[0];
  double s = 0.0, s2 = 0.0;
  for (int r = r0; r < r1; r++) {
    int xi = x[(long)r * F + f];
    float pr = xi >= 0 ? (float)xi : alpha * (float)xi;
    double v = (double)pr;
    s += v; s2 += v * v;
  }
  atomicAdd(&sums[2 * f], s);
  atomicAdd(&sums[2 * f + 1], s2);
}

// ---------------- activation pack kernels ----------------

// pack from i8 dots: prelu -> BN sign (stats from st).
__global__ void pack_cl_i8(const signed char* __restrict__ acl, const double2* __restrict__ st,
                           const float* __restrict__ g, const float* __restrict__ b,
                           const float* __restrict__ cp, uint64_t* __restrict__ out,
                           int C, long nwords, int lw) {
  long base = ((long)blockIdx.x * 4 + (threadIdx.x >> 6)) * 8;
  int lane = threadIdx.x & 63;
  float alpha = cp[0];
  for (int j = 0; j < 8; j++) {
    long wid = base + j;
    if (wid >= nwords) return;
    long row = wid >> lw;
    int w = (int)(wid & ((1 << lw) - 1));
    int c = w * 64 + lane;
    double2 s = st[c];
    int xi = acl[row * C + c];
    float pr = xi >= 0 ? (float)xi : alpha * (float)xi;
    float xn = (float)(((double)pr - s.x) * s.y) * g[c] + b[c];
    uint64_t m = __ballot(xn > 0.f);
    if (lane == 0) out[wid] = m;
  }
}

__global__ void pack_cl_i16(const short* __restrict__ acl, const double2* __restrict__ st,
                            const float* __restrict__ g, const float* __restrict__ b,
                            const float* __restrict__ cp, uint64_t* __restrict__ out,
                            int C, long nwords, int lw) {
  long base = ((long)blockIdx.x * 4 + (threadIdx.x >> 6)) * 8;
  int lane = threadIdx.x & 63;
  float alpha = cp[0];
  for (int j = 0; j < 8; j++) {
    long wid = base + j;
    if (wid >= nwords) return;
    long row = wid >> lw;
    int w = (int)(wid & ((1 << lw) - 1));
    int c = w * 64 + lane;
    double2 s = st[c];
    int xi = acl[row * C + c];
    float pr = xi >= 0 ? (float)xi : alpha * (float)xi;
    float xn = (float)(((double)pr - s.x) * s.y) * g[c] + b[c];
    uint64_t m = __ballot(xn > 0.f);
    if (lane == 0) out[wid] = m;
  }
}

// pack sign+nz masks from a3 with finalize_stats INLINED (m,rs from sums).
__global__ void pack_nz_st_i16(const short* __restrict__ x, const double* __restrict__ sums,
                               const float* __restrict__ g, const float* __restrict__ b,
                               const float* __restrict__ cp, uint64_t* __restrict__ out,
                               int R, int F) {
  int Wf = F >> 6;
  long base = ((long)blockIdx.x * 4 + (threadIdx.x >> 6)) * 8;
  int lane = threadIdx.x & 63;
  float alpha = cp[0];
  for (int j = 0; j < 8; j++) {
    long wid = base + j;
    if (wid >= (long)R * Wf) return;
    long r = wid / Wf;
    int w = (int)(wid % Wf);
    int f = w * 64 + lane;
    double m = sums[2 * f] / 128.0;
    double v = sums[2 * f + 1] / 128.0 - m * m;
    double rs = 1.0 / sqrt(v + BN_EPS);
    int xi = x[r * F + f];
    float pr = xi >= 0 ? (float)xi : alpha * (float)xi;
    double d = (double)pr - m;  // exact for lattice values
    float xn = (float)(d * rs) * g[f] + b[f];
    uint64_t sm = __ballot(xn > 0.f);
    uint64_t nm = __ballot(d != 0.0);
    if (lane == 0) { out[2 * wid] = sm; out[2 * wid + 1] = nm; }
  }
}

// ---------------- fused conv + maxpool + prelu (+ BN stats) ----------------

// conv1: i8 dots channel-last [n][961][128] + fused per-block stats.
__global__ __launch_bounds__(256) void conv1_pool3_i8(const uint64_t* __restrict__ rows,
                                                      const uint32_t* __restrict__ wm,
                                                      const float* __restrict__ cp,
                                                      signed char* __restrict__ out,
                                                      double2* __restrict__ pp) {
  __shared__ uint64_t rL[192];
  __shared__ uint32_t wL[128];
  __shared__ uint32_t mL[61 * 4];
  __shared__ double2 sm[256];
  int n = blockIdx.y, chunk = blockIdx.x, t = threadIdx.x;
  if (t < 192) rL[t] = rows[n * 192 + t];
  if (t < 128) wL[t] = wm[t];
  __syncthreads();
  if (t < 244) {
    int pl = t >> 2, quad = t & 3;
    int pos = chunk * 61 + pl;
    if (pos < 961) {
      int py = pos / 31, px = pos - py * 31;
      int cy = 2 * py + (quad >> 1), cx = 2 * px + (quad & 1);
      uint32_t m = 0;
#pragma unroll
      for (int ci = 0; ci < 3; ci++)
#pragma unroll
        for (int ky = 0; ky < 3; ky++)
          m |= (uint32_t)((rL[ci * 64 + cy + ky] >> cx) & 7) << (ci * 9 + ky * 3);
      mL[pl * 4 + quad] = m;
    }
  }
  __syncthreads();
  int co = t & 127, slot = t >> 7;
  float alpha = cp[0];
  uint32_t w = wL[co];
  double s = 0.0, s2 = 0.0;
  for (int i = slot; i < 61; i += 2) {
    int pos = chunk * 61 + i;
    if (pos >= 961) break;
    int p0 = __popc(mL[4 * i] ^ w);
    int p1 = __popc(mL[4 * i + 1] ^ w);
    int p2 = __popc(mL[4 * i + 2] ^ w);
    int p3 = __popc(mL[4 * i + 3] ^ w);
    int dot = 27 - 2 * min(min(p0, p1), min(p2, p3));
    out[((long)n * 961 + pos) * 128 + co] = (signed char)dot;
    float pr = dot >= 0 ? (float)dot : alpha * (float)dot;
    double v = (double)pr;
    s += v; s2 += v * v;
  }
  sm[t] = make_double2(s, s2);
  __syncthreads();
  if (t < 128) {
    double2 a = sm[t], b = sm[t + 128];
    pp[((long)n * 16 + chunk) * 128 + t] = make_double2(a.x + b.x, a.y + b.y);
  }
}

// conv2: i16 dots CL [n][196][256] + fused stats (R7 carry core).
template <int W, int IH, int PH, int CHUNK>
__global__ __attribute__((amdgpu_flat_work_group_size(256, 256),
                          amdgpu_waves_per_eu(3, 4)))
void convp_carry_i16(const uint64_t* __restrict__ in, const uint64_t* __restrict__ wt,
                     const float* __restrict__ cp, short* __restrict__ out,
                     double2* __restrict__ pp, int CO) {
  __shared__ uint64_t sIn[10 * IH * W];
  __shared__ double2 sm[256];
  int n = blockIdx.y;
  int cg = blockIdx.x / CHUNK, chunk = blockIdx.x % CHUNK;
  int t = threadIdx.x, lane = t & 63, slot = t >> 6;
  int r0 = chunk * 8;
  int nr = min(10, IH - r0);
  const uint64_t* src = in + ((long)n * IH + r0) * (IH * W);
  for (int i = t; i < nr * IH * W; i += 256) sIn[i] = src[i];
  int co = cg * 64 + lane;
  uint64_t wr[9 * W];
  const uint64_t* wg = wt + (long)co * (9 * W);
#pragma unroll
  for (int i = 0; i < 9 * W; i++) wr[i] = wg[i];
  __syncthreads();
  int py = chunk * 4 + slot;
  float alpha = cp[0];
  double s = 0.0, s2 = 0.0;
  if (py < PH) {
    const int K = 9 * 64 * W;
    const uint64_t* base = &sIn[(2 * slot) * (IH * W)];
    uint64_t c[4][2 * W];
#pragma unroll
    for (int cy = 0; cy < 4; cy++) {
      const uint64_t* p = &base[(cy * IH) * W];
#pragma unroll
      for (int j = 0; j < 2 * W; j++) c[cy][j] = p[j];
    }
#pragma unroll
    for (int px = 0; px < PH; px++) {
      int a00 = 0, a01 = 0, a10 = 0, a11 = 0;
#pragma unroll
      for (int cy = 0; cy < 4; cy++) {
        uint64_t f[2 * W];
        const uint64_t* fp = &base[(cy * IH + 2 * px + 2) * W];
#pragma unroll
        for (int j = 0; j < 2 * W; j++) f[j] = fp[j];
#pragma unroll
        for (int col = 0; col < 4; col++) {
#pragma unroll
          for (int wd = 0; wd < W; wd++) {
            uint64_t v = (col < 2) ? c[cy][col * W + wd] : f[(col - 2) * W + wd];
#pragma unroll
            for (int dy = 0; dy < 2; dy++) {
              int ky = cy - dy;
              if (ky < 0 || ky > 2) continue;
#pragma unroll
              for (int dx = 0; dx < 2; dx++) {
                int kx = col - dx;
                if (kx < 0 || kx > 2) continue;
                int p = __popcll(v ^ wr[(ky * 3 + kx) * W + wd]);
                if (dy == 0) { if (dx == 0) a00 += p; else a01 += p; }
                else         { if (dx == 0) a10 += p; else a11 += p; }
              }
            }
          }
        }
#pragma unroll
        for (int j = 0; j < 2 * W; j++) c[cy][j] = f[j];
      }
      int dot = K - 2 * min(min(a00, a01), min(a10, a11));
      out[((long)n * PH * PH + py * PH + px) * CO + co] = (short)dot;
      float pr = dot >= 0 ? (float)dot : alpha * (float)dot;
      double v = (double)pr;
      s += v; s2 += v * v;
    }
  }
  sm[t] = make_double2(s, s2);
  __syncthreads();
  if (t < 64) {
    double2 a = sm[t], b = sm[64 + t], cc = sm[128 + t], d = sm[192 + t];
    pp[((long)blockIdx.y * 16 + blockIdx.x) * 64 + t] =
        make_double2(a.x + b.x + cc.x + d.x, a.y + b.y + cc.y + d.y);
  }
}

// conv3: i16 dots channel-major [n][512][36] (R4 half-wave core).
#define TAP2(acc, P, wa, wb) acc += __popcll((P).x ^ (wa)) + __popcll((P).y ^ (wb));
#define ROWT(aL, aR, pA, pB, pC, pD, WX, WY, WZ)                \
  TAP2(aL, pA, WX.x, WX.y) TAP2(aL, pB, WY.x, WY.y)             \
  TAP2(aL, pC, WZ.x, WZ.y)                                      \
  TAP2(aR, pB, WX.x, WX.y) TAP2(aR, pC, WY.x, WY.y)             \
  TAP2(aR, pD, WZ.x, WZ.y)

__global__ __attribute__((amdgpu_flat_work_group_size(256, 256),
                          amdgpu_waves_per_eu(4, 6)))
void convs3_i16(const uint64_t* __restrict__ in, const uint64_t* __restrict__ wt,
                short* __restrict__ out) {
  __shared__ uint64_t sIn[14 * 14 * 4];
  int n = blockIdx.y, cg = blockIdx.x;
  int t = threadIdx.x, lane = t & 63, slot = t >> 6;
  const uint64_t* src = in + (long)n * 784;
  for (int i = t; i < 784; i += 256) sIn[i] = src[i];
  int h = lane >> 5;
  int co = cg * 32 + (lane & 31);
  const uint64_t* wg = wt + co * 36 + 2 * h;
  ulonglong2 W0 = *(const ulonglong2*)(wg + 0);
  ulonglong2 W1 = *(const ulonglong2*)(wg + 4);
  ulonglong2 W2 = *(const ulonglong2*)(wg + 8);
  ulonglong2 W3 = *(const ulonglong2*)(wg + 12);
  ulonglong2 W4 = *(const ulonglong2*)(wg + 16);
  ulonglong2 W5 = *(const ulonglong2*)(wg + 20);
  ulonglong2 W6 = *(const ulonglong2*)(wg + 24);
  ulonglong2 W7 = *(const ulonglong2*)(wg + 28);
  ulonglong2 W8 = *(const ulonglong2*)(wg + 32);
  __syncthreads();
  short* outb = out + ((long)n * 512 + co) * 36;
#pragma unroll
  for (int k = 0; k < 9; k++) {
    int pos = slot + 4 * k;  // 0..35
    int py = pos / 6, px = pos - py * 6;
    const uint64_t* q = sIn + ((2 * py) * 14 + 2 * px) * 4 + 2 * h;
    int a00 = 0, a01 = 0, a10 = 0, a11 = 0;
    {
      ulonglong2 p0 = *(const ulonglong2*)(q + 0);
      ulonglong2 p1 = *(const ulonglong2*)(q + 4);
      ulonglong2 p2 = *(const ulonglong2*)(q + 8);
      ulonglong2 p3 = *(const ulonglong2*)(q + 12);
      ROWT(a00, a01, p0, p1, p2, p3, W0, W1, W2)
    }
    {
      const uint64_t* q1 = q + 56;
      ulonglong2 p0 = *(const ulonglong2*)(q1 + 0);
      ulonglong2 p1 = *(const ulonglong2*)(q1 + 4);
      ulonglong2 p2 = *(const ulonglong2*)(q1 + 8);
      ulonglong2 p3 = *(const ulonglong2*)(q1 + 12);
      ROWT(a00, a01, p0, p1, p2, p3, W3, W4, W5)
      ROWT(a10, a11, p0, p1, p2, p3, W0, W1, W2)
    }
    {
      const uint64_t* q2 = q + 112;
      ulonglong2 p0 = *(const ulonglong2*)(q2 + 0);
      ulonglong2 p1 = *(const ulonglong2*)(q2 + 4);
      ulonglong2 p2 = *(const ulonglong2*)(q2 + 8);
      ulonglong2 p3 = *(const ulonglong2*)(q2 + 12);
      ROWT(a00, a01, p0, p1, p2, p3, W6, W7, W8)
      ROWT(a10, a11, p0, p1, p2, p3, W3, W4, W5)
    }
    {
      const uint64_t* q3 = q + 168;
      ulonglong2 p0 = *(const ulonglong2*)(q3 + 0);
      ulonglong2 p1 = *(const ulonglong2*)(q3 + 4);
      ulonglong2 p2 = *(const ulonglong2*)(q3 + 8);
      ulonglong2 p3 = *(const ulonglong2*)(q3 + 12);
      ROWT(a10, a11, p0, p1, p2, p3, W6, W7, W8)
    }
    int t00 = a00 + __shfl_xor(a00, 32);
    int t01 = a01 + __shfl_xor(a01, 32);
    int t10 = a10 + __shfl_xor(a10, 32);
    int t11 = a11 + __shfl_xor(a11, 32);
    if (h == 0) {
      int dot = 2304 - 2 * min(min(t00, t01), min(t10, t11));
      outb[pos] = (short)dot;
    }
  }
}

// ---------------- binary fc ----------------

// fc0 + epilogue: writes f1 AND per-feature fp64 partials pp3[by][1024]
// (sum, sum^2 over this block's 2 rows) so fc1 needs no reduce pass.
__global__ void fc_bin2_pp(const uint64_t* __restrict__ xp, const uint64_t* __restrict__ wp_t,
                           const float* __restrict__ cp, float* __restrict__ out,
                           double2* __restrict__ pp3, int O, int Wf) {
  __shared__ uint64_t xs[2][288], xz[2][288];
  int r0 = blockIdx.y * 2;
  for (int i = threadIdx.x; i < 2 * Wf; i += blockDim.x) {
    int rr = i / Wf, wd = i - rr * Wf;
    xs[rr][wd] = xp[(((long)(r0 + rr)) * Wf + wd) * 2];
    xz[rr][wd] = xp[(((long)(r0 + rr)) * Wf + wd) * 2 + 1];
  }
  __syncthreads();
  int o = blockIdx.x * blockDim.x + threadIdx.x;
  if (o >= O) return;
  int pc0 = 0, pc1 = 0, nz0 = 0, nz1 = 0;
  for (int wd = 0; wd < Wf; wd++) {
    uint64_t w = wp_t[(long)wd * O + o];
    uint64_t z0 = xz[0][wd], z1 = xz[1][wd];
    pc0 += __popcll((xs[0][wd] ^ w) & z0);
    pc1 += __popcll((xs[1][wd] ^ w) & z1);
    nz0 += __popcll(z0);
    nz1 += __popcll(z1);
  }
  float alpha = cp[0];
  int d0 = nz0 - 2 * pc0, d1 = nz1 - 2 * pc1;
  float v0 = (float)d0, v1 = (float)d1;
  v0 = d0 >= 0 ? v0 : alpha * v0;
  v1 = d1 >= 0 ? v1 : alpha * v1;
  out[(long)r0 * O + o] = v0;
  out[(long)(r0 + 1) * O + o] = v1;
  double dv0 = (double)v0, dv1 = (double)v1;
  pp3[(long)blockIdx.y * O + o] = make_double2(dv0 + dv1, dv0 * dv0 + dv1 * dv1);
}

// entire fc1 block in one kernel: block = row r. Stats per feature from pp3
// (64 partials), BN sign+nz pack into LDS, then 10-output binary dot + scale.
__global__ void fc1_fused(const float* __restrict__ f1, const double2* __restrict__ pp3,
                          const float* __restrict__ g, const float* __restrict__ b,
                          const uint64_t* __restrict__ w4p, const float* __restrict__ cp,
                          const float* __restrict__ scale, float* __restrict__ out) {
  __shared__ uint64_t xs[16], xz[16];
  int r = blockIdx.x, t = threadIdx.x, lane = t & 63, wv = t >> 6;
  for (int it = 0; it < 4; it++) {
    int f = it * 256 + t;
    double s = 0.0, s2 = 0.0;
    for (int y = 0; y < 64; y++) {
      double2 p = pp3[(long)y * 1024 + f];
      s += p.x; s2 += p.y;
    }
    double m = s / 128.0;
    double v = s2 / 128.0 - m * m;
    double rs = 1.0 / sqrt(v + BN_EPS);
    double d = (double)f1[(long)r * 1024 + f] - m;  // exact lattice
    float xn = (float)(d * rs) * g[f] + b[f];
    uint64_t smk = __ballot(xn > 0.f);
    uint64_t nmk = __ballot(d != 0.0);
    if (lane == 0) { xs[it * 4 + wv] = smk; xz[it * 4 + wv] = nmk; }
  }
  __syncthreads();
  if (t < 10) {
    int pc = 0, nzc = 0;
    for (int wd = 0; wd < 16; wd++) {
      uint64_t nz = xz[wd];
      pc += __popcll((xs[wd] ^ w4p[wd * 10 + t]) & nz);
      nzc += __popcll(nz);
    }
    int dot = nzc - 2 * pc;
    float f = (float)dot;
    float alpha = cp[0];
    f = dot >= 0 ? f : alpha * f;
    out[(long)r * 10 + t] = f * scale[0];
  }
}

// ---------------- launch ----------------

extern "C" void kernel_launch(void* const* d_in, const int* in_sizes, int n_in,
                              void* d_out, int out_size, void* d_ws, size_t ws_size,
                              hipStream_t stream) {
  const float* x   = (const float*)d_in[0];
  const float* cg0 = (const float*)d_in[1];
  const float* cb0 = (const float*)d_in[2];
  const float* cw0 = (const float*)d_in[3];
  const float* cp0 = (const float*)d_in[4];
  const float* cg1 = (const float*)d_in[5];
  const float* cb1 = (const float*)d_in[6];
  const float* cw1 = (const float*)d_in[7];
  const float* cp1 = (const float*)d_in[8];
  const float* cg2 = (const float*)d_in[9];
  const float* cb2 = (const float*)d_in[10];
  const float* cw2 = (const float*)d_in[11];
  const float* cp2 = (const float*)d_in[12];
  const float* fg0 = (const float*)d_in[13];
  const float* fb0 = (const float*)d_in[14];
  const float* fw0 = (const float*)d_in[15];
  const float* fp0 = (const float*)d_in[16];
  const float* fg1 = (const float*)d_in[17];
  const float* fb1 = (const float*)d_in[18];
  const float* fw1 = (const float*)d_in[19];
  const float* fp1 = (const float*)d_in[20];
  const float* scl = (const float*)d_in[21];

  char* ws = (char*)d_ws;
  size_t off = 0;
  auto alloc = [&](size_t bytes) {
    size_t r = off;
    off += (bytes + 255) & ~(size_t)255;
    return r;
  };
  const int C1_OFF = 16, C2_OFF = 160;

  double*   sums  = (double*)(ws + alloc(18432L * 2 * sizeof(double)));   // fc0 stats
  double2*  stats = (double2*)(ws + alloc(512L * sizeof(double2)));       // C0..C2 channels
  double*   pplane= (double*)(ws + alloc(128L * 3 * 2 * sizeof(double)));
  double2*  pp1   = (double2*)(ws + alloc(2048L * 128 * sizeof(double2)));
  double2*  pp2   = (double2*)(ws + alloc(2048L * 64 * sizeof(double2)));
  double2*  pp3   = (double2*)(ws + alloc(64L * 1024 * sizeof(double2)));
  uint64_t* rows0 = (uint64_t*)(ws + alloc(128L * 3 * 64 * 8));
  uint32_t* wm1   = (uint32_t*)(ws + alloc(128L * 4));
  signed char* a1 = (signed char*)(ws + alloc(128L * 961 * 128));   // i8 dots, CL
  uint64_t* s1p   = (uint64_t*)(ws + alloc(128L * 961 * 2 * 8));
  uint64_t* w1p   = (uint64_t*)(ws + alloc(256L * 9 * 2 * 8));
  short*    a2    = (short*)(ws + alloc(128L * 196 * 256 * 2));     // i16 dots, CL
  uint64_t* s2p   = (uint64_t*)(ws + alloc(128L * 196 * 4 * 8));
  uint64_t* w2p   = (uint64_t*)(ws + alloc(512L * 9 * 4 * 8));
  short*    a3    = (short*)(ws + alloc(128L * 512 * 36 * 2));      // i16 dots, CM
  uint64_t* s3p   = (uint64_t*)(ws + alloc(128L * 288 * 2 * 8));
  uint64_t* w3p   = (uint64_t*)(ws + alloc(1024L * 288 * 8));       // transposed [288][1024]
  float*    f1    = (float*)(ws + alloc(128L * 1024 * 4));
  uint64_t* w4p   = (uint64_t*)(ws + alloc(10L * 16 * 8));          // transposed [16][10]

  const int B = 256;

  // 1: all weight packs + zero of fc0 atomic region (input-independent)
  // blocks: 1 wm1 | 18 conv2 | 72 conv3 | 9216 fc0 | 5 fc1 | 144 zero = 9456
  pack_weights_all<<<dim3(9456), B, 0, stream>>>(cw0, cw1, cw2, fw0, fw1,
                                                 wm1, w1p, w2p, w3p, w4p,
                                                 sums, 36864);

  // ---- block 0 ----
  reduce_plane_p<<<dim3(3, 128), B, 0, stream>>>(x, pplane, 3, 4096);
  pack_bits_c1_f<<<dim3(768), B, 0, stream>>>(x, pplane, cg0, cb0, rows0, 24576);
  conv1_pool3_i8<<<dim3(16, 128), B, 0, stream>>>(rows0, wm1, cp0, a1, pp1);

  // ---- block 1 ----
  finalize_pp1<<<dim3(128), B, 0, stream>>>(pp1, stats + C1_OFF, 128, 2048, 123008.0);
  pack_cl_i8<<<dim3(7688), B, 0, stream>>>(a1, stats + C1_OFF, cg1, cb1, cp0, s1p, 128, 246016L, 1);
  convp_carry_i16<2, 31, 14, 4><<<dim3(16, 128), B, 0, stream>>>(s1p, w1p, cp1, a2, pp2, 256);

  // ---- block 2 ----
  finalize_pp2<<<dim3(256), B, 0, stream>>>(pp2, stats + C2_OFF, 25088.0);
  pack_cl_i16<<<dim3(3136), B, 0, stream>>>(a2, stats + C2_OFF, cg2, cb2, cp1, s2p, 256, 100352L, 2);
  convs3_i16<<<dim3(16, 128), B, 0, stream>>>(s2p, w2p, a3);

  // ---- fc 0 ----
  reduce_cols2_i16<<<dim3(72, 8), B, 0, stream>>>(a3, cp2, sums, 128, 18432, 16);
  pack_nz_st_i16<<<dim3(1152), B, 0, stream>>>(a3, sums, fg0, fb0, cp2, s3p, 128, 18432);
  fc_bin2_pp<<<dim3(4, 64), B, 0, stream>>>(s3p, w3p, fp0, f1, pp3, 1024, 288);

  // ---- fc 1 (single fused kernel) ----
  fc1_fused<<<dim3(128), B, 0, stream>>>(f1, pp3, fg1, fb1, w4p, fp1, scl, (float*)d_out);
}